// Round 7
// baseline (35154.556 us; speedup 1.0000x reference)
//
#include <hip/hip_runtime.h>
#include <hip/hip_bf16.h>

// ---------------------------------------------------------------------------
// StandardMRALSTM — round 7: fused cell kernel (ONE dispatch per phase).
//  * Block = (cell seg, j-subtile sub, b-quad bq): 64j x 16b x all gates x K512.
//  * Waves <-> j-16-subtiles => each thread's MFMA accs hold ALL gates at its
//    (j,b) elements -> gates epilogue fully in-register. No partials, no
//    second kernel. U/V per-batch select via lane predication.
//  * Split-bf16 MFMA (R6-validated frag layouts), fp32 accum.
//  * R5 lesson: no in-kernel grid sync (51us/barrier on 8 XCDs); dispatch
//    boundaries (~5us) carry the phase ordering.
// ---------------------------------------------------------------------------

#define LL 4
#define HH 512
#define TS 128
#define GG 16
#define BB 64
#define FF 64
#define TT 4
#define FIVE_H 2560
#define LBH (LL * BB * HH)

typedef unsigned short u16;
typedef unsigned int u32;
typedef unsigned long long u64;

typedef short bfrag8 __attribute__((ext_vector_type(8)));   // 8 bf16
typedef float facc4 __attribute__((ext_vector_type(4)));    // 4 fp32

#define SG_OFF    64
#define ZALL_OFF  1024
#define ZMASK_OFF 2048
#define C_OFF     4096
#define PING_OFF  (C_OFF + LBH)                       // 135168
#define HIST_OFF  (PING_OFF + 2 * LBH)                // 397312 (u16 region)

#define WT_STRIDE 72                                   // u16; 144B = 16-mult

__device__ __forceinline__ float bf2f(u16 u) { return __uint_as_float(((u32)u) << 16); }
__device__ __forceinline__ float2 bf2x2(u32 u) {
    float2 r;
    r.x = __uint_as_float(u << 16);
    r.y = __uint_as_float(u & 0xFFFF0000u);
    return r;
}
__device__ __forceinline__ u16 f2bf_rne(float f) {
    u32 x = __float_as_uint(f);
    return (u16)((x + 0x7FFFu + ((x >> 16) & 1u)) >> 16);
}
__device__ __forceinline__ float sigm(float x) { return 1.f / (1.f + expf(-x)); }

template <bool BF>
__device__ __forceinline__ float ldv(const void* p, size_t i) {
    return BF ? bf2f(((const u16*)p)[i]) : ((const float*)p)[i];
}

template <bool BF>
__device__ __forceinline__ float dot16(const void* row, const float* xs) {
    float s = 0.f;
    if (BF) {
        const uint4* p = (const uint4*)row;
        uint4 a = p[0], b4 = p[1];
        float2 v;
        v = bf2x2(a.x);  s += v.x * xs[0]  + v.y * xs[1];
        v = bf2x2(a.y);  s += v.x * xs[2]  + v.y * xs[3];
        v = bf2x2(a.z);  s += v.x * xs[4]  + v.y * xs[5];
        v = bf2x2(a.w);  s += v.x * xs[6]  + v.y * xs[7];
        v = bf2x2(b4.x); s += v.x * xs[8]  + v.y * xs[9];
        v = bf2x2(b4.y); s += v.x * xs[10] + v.y * xs[11];
        v = bf2x2(b4.z); s += v.x * xs[12] + v.y * xs[13];
        v = bf2x2(b4.w); s += v.x * xs[14] + v.y * xs[15];
    } else {
        const float4* p = (const float4*)row;
#pragma unroll
        for (int i = 0; i < 4; ++i) {
            float4 v = p[i];
            s += v.x * xs[4 * i] + v.y * xs[4 * i + 1] + v.z * xs[4 * i + 2] + v.w * xs[4 * i + 3];
        }
    }
    return s;
}

// ---- init A ----------------------------------------------------------------
__global__ void initA_kernel(const u16* __restrict__ bnd_raw, float* __restrict__ ws) {
    size_t i = (size_t)blockIdx.x * 256 + threadIdx.x;
    if (i < LBH) ws[C_OFF + i] = 0.f;
    if (i < 512) ws[SG_OFF + i] = 0.f;
    if (i == 0) {
        int bf = 1;
        for (int j = 0; j < 32; ++j) {
            float v = bf2f(bnd_raw[2 * j]);
            if (!(v >= 0.f && v <= 1.f)) bf = 0;
        }
        ((int*)ws)[0] = bf;
    }
}

// ---- init B ----------------------------------------------------------------
template <bool BF>
__device__ void initB_body(const void* xin, float* ws) {
    int tk = blockIdx.x;
    int t = tk >> 2, k = tk & 3;
    int b = threadIdx.x;
    bool z = false;
    size_t base = (size_t)b * TS * FF + (size_t)t * FF + k * GG;
#pragma unroll
    for (int g = 0; g < GG; ++g) {
        float v = ldv<BF>(xin, base + g);
        z |= !(v != v);
    }
    u64 m = __ballot(z);
    if (b == 0) {
        ((u64*)(ws + ZMASK_OFF))[tk] = m;
        ((int*)(ws + ZALL_OFF))[tk] = (m == ~0ull) ? 1 : 0;
    }
}
__global__ __launch_bounds__(64) void initB_kernel(const void* xin, float* ws) {
    int mode = ((const int*)ws)[0];
    if (mode) initB_body<true>(xin, ws);
    else      initB_body<false>(xin, ws);
}

// ---- per-phase metadata ----------------------------------------------------
template <bool BF>
__device__ __forceinline__ void phase_meta(const void* bnd, const float* ws,
                                           int tau, int s,
                                           int& t, int& k, int& mcase, int& azf) {
    k = (tau & 1) + 2 * s;
    t = (tau - k) >> 1;
    mcase = 4; azf = 0;
    if (t < 0 || t >= TS) { t = -1; return; }
    const float* sgsum = ws + SG_OFF;
    bool p_hi = (t == 0) ? (ldv<BF>(bnd, (size_t)k * TS) > 0.5f) : (sgsum[(t - 1) * 4 + k] > 16384.f);
    bool l_hi = (k == 0) ? (ldv<BF>(bnd, (size_t)t) > 0.5f) : (sgsum[t * 4 + (k - 1)] > 16384.f);
    mcase = p_hi ? (l_hi ? 3 : 2) : (l_hi ? 1 : 4);
    azf = ((const int*)(ws + ZALL_OFF))[t * 4 + k] ? 0 : 1;
}

// ---- one K=512 MFMA pass over one matrix (BF) ------------------------------
// wt: u16[NG*64][WT_STRIDE]; hB: u16[2][8][16][8] per-chunk frags.
template <int NG>
__device__ __forceinline__ void mfma_pass(const u16* M, int RS, const float* hv,
                                          int gs, int sub, int bq,
                                          u16* wt, u16* hB, facc4* acc,
                                          int tid, int wave, int m, int qd) {
    for (int chunk = 0; chunk < 8; ++chunk) {
        __syncthreads();
        // stage weights: NG*64 rows x 64 cols (bf16, exact)
#pragma unroll
        for (int rr = 0; rr < 2; ++rr) {
            int r = rr * 128 + (tid >> 1);
            if (r < NG * 64) {
                int gi = r >> 6, rl = r & 63;
                int gate = (NG == 4) ? gi : gi + 1;
                int gb = (gate < 3) ? gate * 512 : 2048;
                const u16* src = M + (size_t)(gb + sub * 64 + rl) * RS + chunk * 64 + (tid & 1) * 32;
                uint4* dst = (uint4*)&wt[r * WT_STRIDE + (tid & 1) * 32];
#pragma unroll
                for (int i = 0; i < 4; ++i) dst[i] = *(const uint4*)(src + 8 * i);
            }
        }
        // stage h chunk: fp32 [c][64b] -> hi/lo bf16 B-frags [kg][n][jj]
        {
            int kg = tid >> 5, n = (tid >> 1) & 15, hf = tid & 1;
            int c0 = chunk * 64 + kg * 8 + hf * 4;
            const float* hp = hv + (size_t)c0 * BB + bq * 16 + n;
            float v0 = hp[0], v1 = hp[64], v2 = hp[128], v3 = hp[192];
            u16 h0 = f2bf_rne(v0), h1 = f2bf_rne(v1), h2 = f2bf_rne(v2), h3 = f2bf_rne(v3);
            u16 l0 = f2bf_rne(v0 - bf2f(h0)), l1 = f2bf_rne(v1 - bf2f(h1));
            u16 l2 = f2bf_rne(v2 - bf2f(h2)), l3 = f2bf_rne(v3 - bf2f(h3));
            int bi = (kg * 16 + n) * 8 + hf * 4;
            *(uint2*)&hB[bi] = make_uint2((u32)h0 | ((u32)h1 << 16), (u32)h2 | ((u32)h3 << 16));
            *(uint2*)&hB[1024 + bi] = make_uint2((u32)l0 | ((u32)l1 << 16), (u32)l2 | ((u32)l3 << 16));
        }
        __syncthreads();
#pragma unroll
        for (int kb = 0; kb < 2; ++kb) {
            int kgq = kb * 4 + qd;
            bfrag8 bh = *(const bfrag8*)&hB[(kgq * 16 + m) * 8];
            bfrag8 bl = *(const bfrag8*)&hB[1024 + (kgq * 16 + m) * 8];
#pragma unroll
            for (int gi = 0; gi < NG; ++gi) {
                bfrag8 a = *(const bfrag8*)&wt[(gi * 64 + wave * 16 + m) * WT_STRIDE + kb * 32 + qd * 8];
                acc[gi] = __builtin_amdgcn_mfma_f32_16x16x32_bf16(a, bh, acc[gi], 0, 0, 0);
                acc[gi] = __builtin_amdgcn_mfma_f32_16x16x32_bf16(a, bl, acc[gi], 0, 0, 0);
            }
        }
    }
}

// ---- f32 scalar pass (correctness fallback; inputs are bf16 in practice) ---
template <int NG>
__device__ __forceinline__ void f32_pass(const float* Mf, int RS, const float* hv,
                                         int gs, int sub, int bq,
                                         float* hs, facc4* acc,
                                         int tid, int wave, int m, int qd) {
    __syncthreads();
    for (int idx = tid; idx < HH * 16; idx += 256)
        hs[idx] = hv[(size_t)(idx >> 4) * BB + bq * 16 + (idx & 15)];
    __syncthreads();
#pragma unroll
    for (int gi = 0; gi < NG; ++gi) {
        int gate = (NG == 4) ? gi : gi + 1;
        int gb = (gate < 3) ? gate * 512 : 2048;
#pragma unroll
        for (int reg = 0; reg < 4; ++reg) {
            int jl = wave * 16 + qd * 4 + reg;
            const float* row = Mf + (size_t)(gb + sub * 64 + jl) * RS;
            float s = 0.f;
            for (int c = 0; c < HH; ++c) s += row[c] * hs[c * 16 + m];
            acc[gi][reg] += s;
        }
    }
}

// ---- fused cell compute ----------------------------------------------------
template <int NG, bool BF>
__device__ void cell_compute(const void* xin, const void* Wm, const void* Zm,
                             const void* Um, const void* Vm, const void* Jm,
                             const void* bb, float* ws,
                             u16* wt, u16* hB, float (*xs)[GG + 1], float* red,
                             int t, int k, int mcase, int azf, int sub, int bq) {
    int tid = threadIdx.x;
    int wave = tid >> 6, lane = tid & 63;
    int m = lane & 15, qd = lane >> 4;

    u64 zmask = ((const u64*)(ws + ZMASK_OFF))[t * 4 + k];
    bool doA = (t > 0);
    bool doU = (k > 0) && (mcase != 2) && (zmask != 0ull);
    bool doV = (k > 0) && (mcase != 2) && azf;
    int kn = (k + 1 < LL) ? k + 1 : LL - 1;
    int km = (k > 0) ? k - 1 : 0;
    const float* prev = ws + PING_OFF + (size_t)((t + 1) & 1) * LBH;   // [k][c][b]
    float* cur = ws + PING_OFF + (size_t)(t & 1) * LBH;
    const float* hA = prev + (size_t)((mcase == 1) ? k : kn) * HH * BB;
    const float* hU = cur + (size_t)km * HH * BB;
    int gs = (NG == 4) ? 0 : 1;

    facc4 accA[NG], accB[NG], accV[NG];
#pragma unroll
    for (int gi = 0; gi < NG; ++gi) {
        accA[gi] = (facc4){0.f, 0.f, 0.f, 0.f};
        accB[gi] = (facc4){0.f, 0.f, 0.f, 0.f};
        accV[gi] = (facc4){0.f, 0.f, 0.f, 0.f};
    }

    if (BF) {
        const u16* WZ = (const u16*)((mcase == 1) ? Wm : Zm) + (size_t)k * FIVE_H * HH;
        if (doA) mfma_pass<NG>(WZ, HH, hA, gs, sub, bq, wt, hB, accA, tid, wave, m, qd);
        if (doU) mfma_pass<NG>((const u16*)Um + (size_t)k * FIVE_H * (HH + GG), HH + GG, hU,
                               gs, sub, bq, wt, hB, accB, tid, wave, m, qd);
        if (doV) mfma_pass<NG>((const u16*)Vm + (size_t)k * FIVE_H * HH, HH, hU,
                               gs, sub, bq, wt, hB, accV, tid, wave, m, qd);
    } else {
        float* hs = (float*)wt;   // alias (36 KB >= 32 KB)
        const float* WZ = (const float*)((mcase == 1) ? Wm : Zm) + (size_t)k * FIVE_H * HH;
        if (doA) f32_pass<NG>(WZ, HH, hA, gs, sub, bq, hs, accA, tid, wave, m, qd);
        if (doU) f32_pass<NG>((const float*)Um + (size_t)k * FIVE_H * (HH + GG), HH + GG, hU,
                              gs, sub, bq, hs, accB, tid, wave, m, qd);
        if (doV) f32_pass<NG>((const float*)Vm + (size_t)k * FIVE_H * HH, HH, hU,
                              gs, sub, bq, hs, accV, tid, wave, m, qd);
    }
    __syncthreads();   // xs staged; LDS quiet

    float* cbuf = ws + C_OFF;
    u16* hist = (u16*)(ws + HIST_OFF);
    int bg = bq * 16 + m;
    bool zb = (zmask >> bg) & 1ull;
    const float* xv = &xs[m][0];
    float sgacc = 0.f;

#pragma unroll
    for (int reg = 0; reg < 4; ++reg) {
        int j = sub * 64 + wave * 16 + qd * 4 + reg;
        float pre[NG];
#pragma unroll
        for (int gi = 0; gi < NG; ++gi) {
            int gate = (NG == 4) ? gi : gi + 1;
            int gb2 = (gate < 3) ? gate * 512 : 2048;
            float p = ldv<BF>(bb, (size_t)k * FIVE_H + gb2 + j);
            if (doA) p += accA[gi][reg];
            if (mcase == 2) {
                if (zb) {
                    const void* row = BF
                        ? (const void*)((const u16*)Jm + ((size_t)k * FIVE_H + gb2 + j) * GG)
                        : (const void*)((const float*)Jm + ((size_t)k * FIVE_H + gb2 + j) * GG);
                    p += dot16<BF>(row, xv);
                }
            } else {
                if (zb) {
                    if (doU) p += accB[gi][reg];
                    const void* row = BF
                        ? (const void*)((const u16*)Um + ((size_t)k * FIVE_H + gb2 + j) * (HH + GG) + HH)
                        : (const void*)((const float*)Um + ((size_t)k * FIVE_H + gb2 + j) * (HH + GG) + HH);
                    p += dot16<BF>(row, xv);
                } else {
                    if (doV) p += accV[gi][reg];
                }
            }
            pre[gi] = p;
        }
        int ig = (NG == 4) ? 1 : 0;
        float gg = tanhf(pre[ig]);
        float ii = sigm(pre[ig + 1]);
        float sgv = fminf(fmaxf((pre[ig + 2] + 1.f) * 0.5f, 0.f), 1.f);
        size_t sidx = ((size_t)k * HH + j) * BB + bg;
        float cn;
        if (NG == 4) {
            float f = sigm(pre[0]);
            cn = f * cbuf[sidx] + ii * gg;
        } else {
            cn = ii * gg;
        }
        cbuf[sidx] = cn;
        float hn = (t > 0) ? prev[sidx] : 0.f;
        cur[sidx] = hn;
        hist[((size_t)(t * 4 + k) * HH + j) * BB + bg] = f2bf_rne(hn);
        sgacc += sgv;
    }
#pragma unroll
    for (int off = 32; off > 0; off >>= 1) sgacc += __shfl_down(sgacc, off);
    if (lane == 0) red[wave] = sgacc;
    __syncthreads();
    if (tid == 0)
        atomicAdd(&ws[SG_OFF + t * 4 + k], red[0] + red[1] + red[2] + red[3]);
}

// ---- m4 cheap path ---------------------------------------------------------
template <bool BF>
__device__ void cell_m4(const void* bb, float* ws, float* red, int t, int k, int sub, int bq) {
    int tid = threadIdx.x;
    int wave = tid >> 6, lane = tid & 63;
    int m = lane & 15, qd = lane >> 4;
    float* cbuf = ws + C_OFF;
    const float* prev = ws + PING_OFF + (size_t)((t + 1) & 1) * LBH;
    float* cur = ws + PING_OFF + (size_t)(t & 1) * LBH;
    u16* hist = (u16*)(ws + HIST_OFF);
    int bg = bq * 16 + m;
    float sgacc = 0.f;
    (void)prev;
#pragma unroll
    for (int reg = 0; reg < 4; ++reg) {
        int j = sub * 64 + wave * 16 + qd * 4 + reg;
        size_t sidx = ((size_t)k * HH + j) * BB + bg;
        float c = cbuf[sidx];
        float o = sigm(ldv<BF>(bb, (size_t)k * FIVE_H + 1536 + j));
        float hn = o * tanhf(c);
        float bsg = ldv<BF>(bb, (size_t)k * FIVE_H + 2048 + j);
        float sgv = fminf(fmaxf((bsg + 1.f) * 0.5f, 0.f), 1.f);
        cur[sidx] = hn;
        hist[((size_t)(t * 4 + k) * HH + j) * BB + bg] = f2bf_rne(hn);
        sgacc += sgv;
    }
#pragma unroll
    for (int off = 32; off > 0; off >>= 1) sgacc += __shfl_down(sgacc, off);
    if (lane == 0) red[wave] = sgacc;
    __syncthreads();
    if (tid == 0)
        atomicAdd(&ws[SG_OFF + t * 4 + k], red[0] + red[1] + red[2] + red[3]);
}

// ---- per-phase fused kernel ------------------------------------------------
__global__ __launch_bounds__(256) void cell_kernel(
    const void* xin, const void* Wm, const void* Zm, const void* Um,
    const void* Vm, const void* Jm, const void* bb, const void* bnd,
    float* ws, int tau) {
    __shared__ __align__(16) u16 wt[256 * WT_STRIDE];   // 36864 B
    __shared__ __align__(16) u16 hB[2048];              // 4096 B
    __shared__ float xs[16][GG + 1];
    __shared__ float red[4];

    int mode = ((const int*)ws)[0];
    int seg = blockIdx.x >> 5, sub = (blockIdx.x >> 2) & 7, bq = blockIdx.x & 3;
    int t, k, mcase, azf;
    if (mode) phase_meta<true>(bnd, ws, tau, seg, t, k, mcase, azf);
    else      phase_meta<false>(bnd, ws, tau, seg, t, k, mcase, azf);
    if (t < 0) return;

    // stage x for this bq's 16 batches (NaN -> 0)
    {
        int bl = threadIdx.x >> 4, i = threadIdx.x & 15;
        size_t xi = (size_t)(bq * 16 + bl) * TS * FF + (size_t)t * FF + k * GG + i;
        float v = mode ? ldv<true>(xin, xi) : ldv<false>(xin, xi);
        xs[bl][i] = (v != v) ? 0.f : v;
    }

    if (mcase == 4) {
        __syncthreads();
        if (mode) cell_m4<true>(bb, ws, red, t, k, sub, bq);
        else      cell_m4<false>(bb, ws, red, t, k, sub, bq);
        return;
    }
    if (mode) {
        if (mcase == 1) cell_compute<4, true>(xin, Wm, Zm, Um, Vm, Jm, bb, ws, wt, hB, xs, red, t, k, mcase, azf, sub, bq);
        else            cell_compute<3, true>(xin, Wm, Zm, Um, Vm, Jm, bb, ws, wt, hB, xs, red, t, k, mcase, azf, sub, bq);
    } else {
        if (mcase == 1) cell_compute<4, false>(xin, Wm, Zm, Um, Vm, Jm, bb, ws, wt, hB, xs, red, t, k, mcase, azf, sub, bq);
        else            cell_compute<3, false>(xin, Wm, Zm, Um, Vm, Jm, bb, ws, wt, hB, xs, red, t, k, mcase, azf, sub, bq);
    }
}

// ---- excitation epilogue (unchanged from R6; hist [tk][j][b]) --------------
template <bool BF>
__device__ void excite_body(const float* ws, float* smem, const void* Qm,
                            const void* Rm, const void* Wom, const void* bom,
                            void* out) {
    float (*sh_hcat)[LL * HH] = (float (*)[LL * HH])smem;
    float (*sh_r)[HH] = (float (*)[HH])(smem + TT * LL * HH);
    const u16* hhist = (const u16*)(ws + HIST_OFF);
    int tid = threadIdx.x;
    int b = blockIdx.x >> 5;
    int t0 = (blockIdx.x & 31) * TT;

    for (int idx = tid; idx < TT * LL * HH; idx += 256) {
        int tt = idx / (LL * HH);
        int f = idx % (LL * HH);
        int kk = f / HH, j = f % HH;
        sh_hcat[tt][f] = bf2f(hhist[((size_t)((t0 + tt) * 4 + kk) * HH + j) * BB + b]);
    }
    __syncthreads();

    int h0 = tid * 2;
    float acc0[TT] = {0, 0, 0, 0}, acc1[TT] = {0, 0, 0, 0};
    for (int kk = 0; kk < LL; ++kk) {
        float r0[TT] = {0, 0, 0, 0}, r1[TT] = {0, 0, 0, 0};
        if (BF) {
            const u32* qp = (const u32*)((const u16*)Qm + (size_t)kk * (LL * HH) * HH) + tid;
#pragma unroll 4
            for (int f = 0; f < LL * HH; ++f) {
                float2 qv = bf2x2(qp[(size_t)f * 256]);
#pragma unroll
                for (int tt = 0; tt < TT; ++tt) {
                    float hc = sh_hcat[tt][f];
                    r0[tt] += qv.x * hc;
                    r1[tt] += qv.y * hc;
                }
            }
        } else {
            const float2* qp = (const float2*)((const float*)Qm + (size_t)kk * (LL * HH) * HH) + tid;
#pragma unroll 4
            for (int f = 0; f < LL * HH; ++f) {
                float2 qv = qp[(size_t)f * 256];
#pragma unroll
                for (int tt = 0; tt < TT; ++tt) {
                    float hc = sh_hcat[tt][f];
                    r0[tt] += qv.x * hc;
                    r1[tt] += qv.y * hc;
                }
            }
        }
        __syncthreads();
#pragma unroll
        for (int tt = 0; tt < TT; ++tt) {
            sh_r[tt][h0]     = 1.f / (1.f + expf(-r0[tt]));
            sh_r[tt][h0 + 1] = 1.f / (1.f + expf(-r1[tt]));
        }
        __syncthreads();
        float m0[TT] = {0, 0, 0, 0}, m1v[TT] = {0, 0, 0, 0};
        if (BF) {
            const u32* rp = (const u32*)((const u16*)Rm + (size_t)kk * HH * HH) + tid;
#pragma unroll 4
            for (int hh2 = 0; hh2 < HH; ++hh2) {
                float2 rv = bf2x2(rp[(size_t)hh2 * 256]);
#pragma unroll
                for (int tt = 0; tt < TT; ++tt) {
                    float rr = sh_r[tt][hh2];
                    m0[tt] += rv.x * rr;
                    m1v[tt] += rv.y * rr;
                }
            }
        } else {
            const float2* rp = (const float2*)((const float*)Rm + (size_t)kk * HH * HH) + tid;
#pragma unroll 4
            for (int hh2 = 0; hh2 < HH; ++hh2) {
                float2 rv = rp[(size_t)hh2 * 256];
#pragma unroll
                for (int tt = 0; tt < TT; ++tt) {
                    float rr = sh_r[tt][hh2];
                    m0[tt] += rv.x * rr;
                    m1v[tt] += rv.y * rr;
                }
            }
        }
#pragma unroll
        for (int tt = 0; tt < TT; ++tt) {
            acc0[tt] += m0[tt] * sh_hcat[tt][kk * HH + h0];
            acc1[tt] += m1v[tt] * sh_hcat[tt][kk * HH + h0 + 1];
        }
    }
    __syncthreads();
#pragma unroll
    for (int tt = 0; tt < TT; ++tt) {
        sh_r[tt][h0]     = fmaxf(acc0[tt], 0.f);
        sh_r[tt][h0 + 1] = fmaxf(acc1[tt], 0.f);
    }
    __syncthreads();
    {
        int tt = tid >> 6, f = tid & 63;
        float acc = 0.f;
        if (BF) {
            const uint4* wp = (const uint4*)((const u16*)Wom + (size_t)f * HH);
            const float4* ev = (const float4*)sh_r[tt];
#pragma unroll 8
            for (int it = 0; it < HH / 8; ++it) {
                uint4 qv = wp[it];
                float4 e0 = ev[2 * it], e1 = ev[2 * it + 1];
                float2 a0 = bf2x2(qv.x), a1 = bf2x2(qv.y), a2 = bf2x2(qv.z), a3 = bf2x2(qv.w);
                acc += a0.x * e0.x + a0.y * e0.y + a1.x * e0.z + a1.y * e0.w +
                       a2.x * e1.x + a2.y * e1.y + a3.x * e1.z + a3.y * e1.w;
            }
        } else {
            const float4* wp = (const float4*)((const float*)Wom + (size_t)f * HH);
            const float4* ev = (const float4*)sh_r[tt];
#pragma unroll 8
            for (int it = 0; it < HH / 4; ++it) {
                float4 qv = wp[it], e = ev[it];
                acc += qv.x * e.x + qv.y * e.y + qv.z * e.z + qv.w * e.w;
            }
        }
        acc += ldv<BF>(bom, f);
        size_t oidx = ((size_t)b * TS + (t0 + tt)) * FF + f;
        if (BF) ((u16*)out)[oidx] = f2bf_rne(acc);
        else    ((float*)out)[oidx] = acc;
    }
}

__global__ __launch_bounds__(256) void excite_kernel(
    const float* ws, const void* Qm, const void* Rm, const void* Wom,
    const void* bom, void* out) {
    extern __shared__ float smem[];
    int mode = ((const int*)ws)[0];
    if (mode) excite_body<true>(ws, smem, Qm, Rm, Wom, bom, out);
    else      excite_body<false>(ws, smem, Qm, Rm, Wom, bom, out);
}

extern "C" void kernel_launch(void* const* d_in, const int* in_sizes, int n_in,
                              void* d_out, int out_size, void* d_ws, size_t ws_size,
                              hipStream_t stream) {
    const void* xin = d_in[0];
    const void* Wm  = d_in[1];
    const void* Zm  = d_in[2];
    const void* Um  = d_in[3];
    const void* Vm  = d_in[4];
    const void* Jm  = d_in[5];
    const void* bb  = d_in[6];
    const void* bnd = d_in[7];
    const void* Qm  = d_in[8];
    const void* Rm  = d_in[9];
    const void* Wo  = d_in[10];
    const void* bo  = d_in[11];
    float* ws = (float*)d_ws;

    initA_kernel<<<dim3(512), dim3(256), 0, stream>>>((const u16*)bnd, ws);
    initB_kernel<<<dim3(512), dim3(64), 0, stream>>>(xin, ws);
    for (int tau = 0; tau < 2 * TS + LL - 2; ++tau)   // 258 phases, 1 dispatch each
        cell_kernel<<<dim3(64), dim3(256), 0, stream>>>(xin, Wm, Zm, Um, Vm, Jm, bb, bnd, ws, tau);
    size_t exc_smem = (TT * LL * HH + TT * HH) * sizeof(float);  // 40 KB
    excite_kernel<<<dim3(2048), dim3(256), exc_smem, stream>>>(
        ws, Qm, Rm, Wo, bo, d_out);
}

// Round 8
// 6711.624 us; speedup vs baseline: 5.2379x; 5.2379x over previous
//
#include <hip/hip_runtime.h>
#include <hip/hip_bf16.h>

// ---------------------------------------------------------------------------
// StandardMRALSTM — round 8: R6 scan (verbatim, proven 6.67ms) + MFMA excite.
//  * R7 lesson: 64-block fused cell = latency-bound disaster (136us/phase).
//    Scan needs many small blocks; revert to R6's 768-block K-split GEMM.
//  * Excite v2 (bf16 mode): 3-stage MFMA pipeline over 4 t-slices of 32,
//    scratch in the dead scan region (r fp16 8MB + excited bf16 2MB < 14MB).
//    E1: r=sigmoid(Q^T hcat) bf16 MFMA; E2: mul1=R^T r f16 MFMA + hbg fold;
//    E3: out=Wo excited + bo bf16 MFMA. f32 mode keeps old scalar excite.
// ---------------------------------------------------------------------------

#define LL 4
#define HH 512
#define TS 128
#define GG 16
#define BB 64
#define FF 64
#define TT 4
#define FIVE_H 2560
#define LBH (LL * BB * HH)

typedef unsigned short u16;
typedef unsigned int u32;
typedef unsigned long long u64;

typedef short bfrag8 __attribute__((ext_vector_type(8)));     // 8 bf16
typedef _Float16 hfrag8 __attribute__((ext_vector_type(8)));  // 8 f16
typedef float facc4 __attribute__((ext_vector_type(4)));      // 4 fp32

#define SG_OFF    64
#define ZALL_OFF  1024
#define ZMASK_OFF 2048
#define C_OFF     4096
#define PING_OFF  (C_OFF + LBH)                       // 135168
#define PART_OFF  (PING_OFF + 2 * LBH)                // 397312
#define PART_SEG  (12 * 4 * HH * BB)                  // 1572864 floats per seg
#define HIST_OFF  (PART_OFF + 2 * PART_SEG)           // 3543040 (u16 region)

// excite scratch (floats; dead scan region [1024, HIST_OFF))
#define R_OFF     1024                                 // r fp16 [2048][2048] u16 (8MB)
#define EXC_OFF   (R_OFF + 2048 * 2048 / 2)            // excited bf16 [512][2048] u16 (2MB)

__device__ __forceinline__ float bf2f(u16 u) { return __uint_as_float(((u32)u) << 16); }
__device__ __forceinline__ float2 bf2x2(u32 u) {
    float2 r;
    r.x = __uint_as_float(u << 16);
    r.y = __uint_as_float(u & 0xFFFF0000u);
    return r;
}
__device__ __forceinline__ u16 f2bf_rne(float f) {
    u32 x = __float_as_uint(f);
    return (u16)((x + 0x7FFFu + ((x >> 16) & 1u)) >> 16);
}
__device__ __forceinline__ float sigm(float x) { return 1.f / (1.f + expf(-x)); }

template <bool BF>
__device__ __forceinline__ float ldv(const void* p, size_t i) {
    return BF ? bf2f(((const u16*)p)[i]) : ((const float*)p)[i];
}

template <bool BF>
__device__ __forceinline__ float dot16(const void* row, const float* xs) {
    float s = 0.f;
    if (BF) {
        const uint4* p = (const uint4*)row;
        uint4 a = p[0], b4 = p[1];
        float2 v;
        v = bf2x2(a.x);  s += v.x * xs[0]  + v.y * xs[1];
        v = bf2x2(a.y);  s += v.x * xs[2]  + v.y * xs[3];
        v = bf2x2(a.z);  s += v.x * xs[4]  + v.y * xs[5];
        v = bf2x2(a.w);  s += v.x * xs[6]  + v.y * xs[7];
        v = bf2x2(b4.x); s += v.x * xs[8]  + v.y * xs[9];
        v = bf2x2(b4.y); s += v.x * xs[10] + v.y * xs[11];
        v = bf2x2(b4.z); s += v.x * xs[12] + v.y * xs[13];
        v = bf2x2(b4.w); s += v.x * xs[14] + v.y * xs[15];
    } else {
        const float4* p = (const float4*)row;
#pragma unroll
        for (int i = 0; i < 4; ++i) {
            float4 v = p[i];
            s += v.x * xs[4 * i] + v.y * xs[4 * i + 1] + v.z * xs[4 * i + 2] + v.w * xs[4 * i + 3];
        }
    }
    return s;
}

// ---- init A ----------------------------------------------------------------
__global__ void initA_kernel(const u16* __restrict__ bnd_raw, float* __restrict__ ws) {
    size_t i = (size_t)blockIdx.x * 256 + threadIdx.x;
    if (i < LBH) ws[C_OFF + i] = 0.f;
    if (i < 512) ws[SG_OFF + i] = 0.f;
    if (i == 0) {
        int bf = 1;
        for (int j = 0; j < 32; ++j) {
            float v = bf2f(bnd_raw[2 * j]);
            if (!(v >= 0.f && v <= 1.f)) bf = 0;
        }
        ((int*)ws)[0] = bf;
    }
}

// ---- init B ----------------------------------------------------------------
template <bool BF>
__device__ void initB_body(const void* xin, float* ws) {
    int tk = blockIdx.x;
    int t = tk >> 2, k = tk & 3;
    int b = threadIdx.x;
    bool z = false;
    size_t base = (size_t)b * TS * FF + (size_t)t * FF + k * GG;
#pragma unroll
    for (int g = 0; g < GG; ++g) {
        float v = ldv<BF>(xin, base + g);
        z |= !(v != v);
    }
    u64 m = __ballot(z);
    if (b == 0) {
        ((u64*)(ws + ZMASK_OFF))[tk] = m;
        ((int*)(ws + ZALL_OFF))[tk] = (m == ~0ull) ? 1 : 0;
    }
}
__global__ __launch_bounds__(64) void initB_kernel(const void* xin, float* ws) {
    int mode = ((const int*)ws)[0];
    if (mode) initB_body<true>(xin, ws);
    else      initB_body<false>(xin, ws);
}

// ---- per-phase metadata ----------------------------------------------------
template <bool BF>
__device__ __forceinline__ void phase_meta(const void* bnd, const float* ws,
                                           int tau, int s,
                                           int& t, int& k, int& mcase, int& azf, int& nblk) {
    k = (tau & 1) + 2 * s;
    t = (tau - k) >> 1;
    mcase = 4; azf = 0; nblk = 0;
    if (t < 0 || t >= TS) { t = -1; return; }
    const float* sgsum = ws + SG_OFF;
    bool p_hi = (t == 0) ? (ldv<BF>(bnd, (size_t)k * TS) > 0.5f) : (sgsum[(t - 1) * 4 + k] > 16384.f);
    bool l_hi = (k == 0) ? (ldv<BF>(bnd, (size_t)t) > 0.5f) : (sgsum[t * 4 + (k - 1)] > 16384.f);
    mcase = p_hi ? (l_hi ? 3 : 2) : (l_hi ? 1 : 4);
    azf = ((const int*)(ws + ZALL_OFF))[t * 4 + k] ? 0 : 1;
    if (mcase == 4) return;
    int gs = (mcase == 1) ? 0 : 1, ng = 4 - gs;
    int nW = (t > 0) ? ng : 0;
    int nU = ((mcase == 1 || mcase == 3) && k > 0) ? ng : 0;
    int nV = azf ? nU : 0;
    nblk = (nW + nU + nV) * 32;
}

// ---- unit -> (matrix, gate) routing ----------------------------------------
struct SlotInfo {
    const u16* M16; const float* Mf; int RS; int path; int g;
    const float* hv;
};
template <bool BF>
__device__ __forceinline__ SlotInfo slot_info(
    const void* Wm, const void* Zm, const void* Um, const void* Vm,
    const float* ws, int unit, int t, int k, int mcase) {
    int gs = (mcase == 1) ? 0 : 1, ng = 4 - gs;
    int nW = (t > 0) ? ng : 0;
    int nU = ((mcase == 1 || mcase == 3) && k > 0) ? ng : 0;
    int mat, g;
    if (unit < nW)            { mat = (mcase == 1) ? 0 : 1; g = gs + unit; }
    else if (unit < nW + nU)  { mat = 2; g = gs + unit - nW; }
    else                      { mat = 3; g = gs + unit - nW - nU; }
    const void* M = (mat == 0) ? Wm : (mat == 1) ? Zm : (mat == 2) ? Um : Vm;
    int kn = (k + 1 < LL) ? k + 1 : LL - 1;
    const float* ping = ws + PING_OFF;
    const float* prev = ping + (size_t)((t + 1) & 1) * LBH;   // [k][c][b]
    const float* cur  = ping + (size_t)(t & 1) * LBH;
    SlotInfo si;
    si.M16 = (const u16*)M; si.Mf = (const float*)M;
    si.RS = (mat == 2) ? (HH + GG) : HH;
    si.path = (mat <= 1) ? 0 : (mat == 2 ? 1 : 2);
    si.g = g;
    si.hv = (mat == 0) ? prev + (size_t)k * HH * BB
          : (mat == 1) ? prev + (size_t)kn * HH * BB
                       : cur + (size_t)(k - 1) * HH * BB;
    return si;
}

// ---- MFMA gemm slot (BF mode) — R6-proven ----------------------------------
#define WT_STRIDE 152
#define HB_OFF 9728
#define HB_PART 8192
__device__ void gemm_slot_bf(const void* Wm, const void* Zm, const void* Um, const void* Vm,
                             float* ws, u16* gsm,
                             int seg, int idx, int t, int k, int mcase) {
    int tid = threadIdx.x;
    int q = idx & 3, sub = (idx >> 2) & 7, unit = idx >> 5;
    SlotInfo si = slot_info<true>(Wm, Zm, Um, Vm, ws, unit, t, k, mcase);
    int gbase = (si.g < 3) ? si.g * 512 : 2048;
    size_t mbase = (size_t)k * FIVE_H * si.RS + (size_t)(gbase + sub * 64) * si.RS + q * 128;
    u16* wt = gsm;
    u16* hB = gsm + HB_OFF;

    {
        int r = tid >> 2, c0 = (tid & 3) * 32;
        const u16* src = si.M16 + mbase + (size_t)r * si.RS + c0;
#pragma unroll
        for (int i = 0; i < 4; ++i)
            *(uint4*)&wt[r * WT_STRIDE + c0 + 8 * i] = *(const uint4*)(src + 8 * i);
    }
    {
        int wave = tid >> 6, lane = tid & 63;
        int bg = lane >> 4, n = lane & 15;
#pragma unroll
        for (int it = 0; it < 4; ++it) {
            int kbq = it * 4 + wave;
            u32 hiw[4], low[4];
#pragma unroll
            for (int jp = 0; jp < 4; ++jp) {
                float v0 = si.hv[(size_t)(q * 128 + kbq * 8 + 2 * jp) * BB + lane];
                float v1 = si.hv[(size_t)(q * 128 + kbq * 8 + 2 * jp + 1) * BB + lane];
                u16 h0 = f2bf_rne(v0), h1 = f2bf_rne(v1);
                u16 l0 = f2bf_rne(v0 - bf2f(h0)), l1 = f2bf_rne(v1 - bf2f(h1));
                hiw[jp] = (u32)h0 | ((u32)h1 << 16);
                low[jp] = (u32)l0 | ((u32)l1 << 16);
            }
            int base = (kbq * 4 + bg) * 128 + n * 8;
            *(uint4*)&hB[base] = make_uint4(hiw[0], hiw[1], hiw[2], hiw[3]);
            *(uint4*)&hB[HB_PART + base] = make_uint4(low[0], low[1], low[2], low[3]);
        }
    }
    __syncthreads();

    int wave = tid >> 6, lane = tid & 63;
    int m = lane & 15, qd = lane >> 4;
    facc4 acc[4];
#pragma unroll
    for (int i = 0; i < 4; ++i) acc[i] = (facc4){0.f, 0.f, 0.f, 0.f};
#pragma unroll
    for (int kb = 0; kb < 4; ++kb) {
        bfrag8 a = *(const bfrag8*)&wt[(wave * 16 + m) * WT_STRIDE + kb * 32 + qd * 8];
        int kbq = kb * 4 + qd;
#pragma unroll
        for (int bg = 0; bg < 4; ++bg) {
            bfrag8 bh = *(const bfrag8*)&hB[(kbq * 4 + bg) * 128 + m * 8];
            bfrag8 bl = *(const bfrag8*)&hB[HB_PART + (kbq * 4 + bg) * 128 + m * 8];
            acc[bg] = __builtin_amdgcn_mfma_f32_16x16x32_bf16(a, bh, acc[bg], 0, 0, 0);
            acc[bg] = __builtin_amdgcn_mfma_f32_16x16x32_bf16(a, bl, acc[bg], 0, 0, 0);
        }
    }
    float* pout = ws + PART_OFF + (size_t)seg * PART_SEG +
                  ((size_t)(si.path * 4 + q) * 4 + si.g) * (size_t)HH * BB;
#pragma unroll
    for (int bg = 0; bg < 4; ++bg)
#pragma unroll
        for (int reg = 0; reg < 4; ++reg)
            pout[(size_t)(sub * 64 + wave * 16 + qd * 4 + reg) * BB + bg * 16 + m] = acc[bg][reg];
}

// ---- fp32 gemm slot (f32 mode) ---------------------------------------------
__device__ void gemm_slot_f32(const void* Wm, const void* Zm, const void* Um, const void* Vm,
                              float* ws, float* wt, float* ht,
                              int seg, int idx, int t, int k, int mcase) {
    int tid = threadIdx.x;
    int q = idx & 3, sub = (idx >> 2) & 7, unit = idx >> 5;
    SlotInfo si = slot_info<false>(Wm, Zm, Um, Vm, ws, unit, t, k, mcase);
    int gbase = (si.g < 3) ? si.g * 512 : 2048;
    size_t mbase = (size_t)k * FIVE_H * si.RS + (size_t)(gbase + sub * 64) * si.RS + q * 128;

    int rg = tid >> 4, bg = tid & 15;
    float acc[4][4] = {{0.f}};
    for (int half = 0; half < 2; ++half) {
        int sr = tid >> 2, scg = (tid & 3) * 16;
        size_t rowoff = mbase + (size_t)sr * si.RS + half * 64 + scg;
#pragma unroll
        for (int i = 0; i < 4; ++i)
            *(float4*)&wt[sr * 68 + scg + 4 * i] = *(const float4*)(si.Mf + rowoff + 4 * i);
        int hc = tid >> 2, hb = (tid & 3) * 16;
        const float* hrow = si.hv + (size_t)(q * 128 + half * 64 + hc) * BB + hb;
#pragma unroll
        for (int i = 0; i < 4; ++i)
            *(float4*)&ht[hc * 68 + hb + 4 * i] = *(const float4*)(hrow + 4 * i);
        __syncthreads();
#pragma unroll 4
        for (int kk4 = 0; kk4 < 64; kk4 += 4) {
            float w[4][4], h[4][4];
#pragma unroll
            for (int j = 0; j < 4; ++j)
                *(float4*)w[j] = *(const float4*)&wt[(rg * 4 + j) * 68 + kk4];
#pragma unroll
            for (int j = 0; j < 4; ++j)
                *(float4*)h[j] = *(const float4*)&ht[(kk4 + j) * 68 + bg * 4];
#pragma unroll
            for (int rj = 0; rj < 4; ++rj)
#pragma unroll
                for (int bj = 0; bj < 4; ++bj)
#pragma unroll
                    for (int j = 0; j < 4; ++j)
                        acc[rj][bj] += w[rj][j] * h[j][bj];
        }
        __syncthreads();
    }
    float* pout = ws + PART_OFF + (size_t)seg * PART_SEG +
                  ((size_t)(si.path * 4 + q) * 4 + si.g) * (size_t)HH * BB;
#pragma unroll
    for (int rj = 0; rj < 4; ++rj) {
        float4 vv = make_float4(acc[rj][0], acc[rj][1], acc[rj][2], acc[rj][3]);
        *(float4*)&pout[(size_t)(sub * 64 + rg * 4 + rj) * BB + bg * 4] = vv;
    }
}

__global__ __launch_bounds__(256) void gemm_phase_kernel(
    const void* Wm, const void* Zm, const void* Um, const void* Vm,
    const void* bnd, float* ws, int tau) {
    __shared__ __align__(16) u16 gsm[26112];
    int mode = ((const int*)ws)[0];
    if (mode) {
        int t0, k0, m0, a0, n0, t1, k1, m1, a1, n1;
        phase_meta<true>(bnd, ws, tau, 0, t0, k0, m0, a0, n0);
        phase_meta<true>(bnd, ws, tau, 1, t1, k1, m1, a1, n1);
        int bid = blockIdx.x;
        if (bid < n0)           gemm_slot_bf(Wm, Zm, Um, Vm, ws, gsm, 0, bid, t0, k0, m0);
        else if (bid < n0 + n1) gemm_slot_bf(Wm, Zm, Um, Vm, ws, gsm, 1, bid - n0, t1, k1, m1);
    } else {
        float* fs = (float*)gsm;
        int t0, k0, m0, a0, n0, t1, k1, m1, a1, n1;
        phase_meta<false>(bnd, ws, tau, 0, t0, k0, m0, a0, n0);
        phase_meta<false>(bnd, ws, tau, 1, t1, k1, m1, a1, n1);
        int bid = blockIdx.x;
        if (bid < n0)           gemm_slot_f32(Wm, Zm, Um, Vm, ws, fs, fs + 4352, 0, bid, t0, k0, m0);
        else if (bid < n0 + n1) gemm_slot_f32(Wm, Zm, Um, Vm, ws, fs, fs + 4352, 1, bid - n0, t1, k1, m1);
    }
}

// ---- gates slot ------------------------------------------------------------
template <bool BF>
__device__ void gates_slot(const void* xin, const void* Um, const void* Jm,
                           const void* bbias, float* ws, float* smem,
                           int seg, int jblk, int t, int k, int mcase, int azf) {
    float (*xs)[GG + 1] = (float (*)[GG + 1])smem;
    float* red = smem + BB * (GG + 1);
    int tid = threadIdx.x;
    int j = jblk * 4 + (tid >> 6);
    int b = tid & 63;

    {
        int b2 = tid >> 2, i0 = (tid & 3) * 4;
#pragma unroll
        for (int i = 0; i < 4; ++i) {
            float v = ldv<BF>(xin, (size_t)b2 * TS * FF + (size_t)t * FF + k * GG + i0 + i);
            xs[b2][i0 + i] = (v != v) ? 0.f : v;
        }
    }
    __syncthreads();
    u64 zm = ((const u64*)(ws + ZMASK_OFF))[t * 4 + k];
    bool zb = (zm >> b) & 1ull;

    float* cbuf = ws + C_OFF;
    const float* part = ws + PART_OFF + (size_t)seg * PART_SEG;
    float* cur = ws + PING_OFF + (size_t)(t & 1) * LBH;
    const float* prev = ws + PING_OFF + (size_t)((t + 1) & 1) * LBH;
    u16* hist = (u16*)(ws + HIST_OFF);
    size_t sidx = ((size_t)k * HH + j) * BB + b;

    float hn, sgv;
    if (mcase == 4) {
        float c = cbuf[sidx];
        float o = sigm(ldv<BF>(bbias, (size_t)k * FIVE_H + 1536 + j));
        hn = o * tanhf(c);
        float bsg = ldv<BF>(bbias, (size_t)k * FIVE_H + 2048 + j);
        sgv = fminf(fmaxf((bsg + 1.f) * 0.5f, 0.f), 1.f);
    } else {
        bool hasWZ = (t > 0);
        bool hasU = (k > 0) && (mcase != 2);
        const float* xv = &xs[b][0];
        auto psum = [&](int path, int g) -> float {
            float s = 0.f;
#pragma unroll
            for (int qq = 0; qq < 4; ++qq)
                s += part[(((size_t)(path * 4 + qq) * 4 + g) * HH + j) * BB + b];
            return s;
        };
        auto pre = [&](int g) -> float {
            int gb = (g < 3) ? g * 512 : 2048;
            float s = ldv<BF>(bbias, (size_t)k * FIVE_H + gb + j);
            if (hasWZ) s += psum(0, g);
            if (mcase == 2) {
                if (zb) {
                    const void* row = BF ? (const void*)((const u16*)Jm + (size_t)k * FIVE_H * GG + (size_t)(gb + j) * GG)
                                         : (const void*)((const float*)Jm + (size_t)k * FIVE_H * GG + (size_t)(gb + j) * GG);
                    s += dot16<BF>(row, xv);
                }
            } else {
                if (zb) {
                    if (hasU) s += psum(1, g);
                    const void* row = BF ? (const void*)((const u16*)Um + (size_t)k * FIVE_H * (HH + GG) + (size_t)(gb + j) * (HH + GG) + HH)
                                         : (const void*)((const float*)Um + (size_t)k * FIVE_H * (HH + GG) + (size_t)(gb + j) * (HH + GG) + HH);
                    s += dot16<BF>(row, xv);
                } else {
                    if (hasU && azf) s += psum(2, g);
                }
            }
            return s;
        };
        float preg = pre(1), prei = pre(2), presg = pre(3);
        float gg = tanhf(preg), ii = sigm(prei);
        float cnew;
        if (mcase == 1) {
            float f = sigm(pre(0));
            cnew = f * cbuf[sidx] + ii * gg;
        } else {
            cnew = ii * gg;
        }
        cbuf[sidx] = cnew;
        hn = (t > 0) ? prev[sidx] : 0.f;
        sgv = fminf(fmaxf((presg + 1.f) * 0.5f, 0.f), 1.f);
    }
    cur[sidx] = hn;
    hist[((size_t)(t * 4 + k) * HH + j) * BB + b] = f2bf_rne(hn);

    float s = sgv;
#pragma unroll
    for (int off = 32; off > 0; off >>= 1) s += __shfl_down(s, off);
    if ((tid & 63) == 0) red[tid >> 6] = s;
    __syncthreads();
    if (tid == 0)
        atomicAdd(&ws[SG_OFF + t * 4 + k], red[0] + red[1] + red[2] + red[3]);
}

template <bool BF>
__device__ void gates_phase_body(const void* xin, const void* Um, const void* Jm,
                                 const void* bbias, const void* bnd, float* ws,
                                 float* smem, int tau) {
    int seg = blockIdx.x >> 7, jblk = blockIdx.x & 127;
    int t, k, mc, az, nb;
    phase_meta<BF>(bnd, ws, tau, seg, t, k, mc, az, nb);
    if (t >= 0)
        gates_slot<BF>(xin, Um, Jm, bbias, ws, smem, seg, jblk, t, k, mc, az);
}
__global__ __launch_bounds__(256) void gates_phase_kernel(
    const void* xin, const void* Um, const void* Jm, const void* bbias,
    const void* bnd, float* ws, int tau) {
    __shared__ float smem[BB * (GG + 1) + 4];
    int mode = ((const int*)ws)[0];
    if (mode) gates_phase_body<true>(xin, Um, Jm, bbias, bnd, ws, smem, tau);
    else      gates_phase_body<false>(xin, Um, Jm, bbias, bnd, ws, smem, tau);
}

// ---- old scalar excite (f32 mode ONLY) -------------------------------------
__global__ __launch_bounds__(256) void excite_f32_kernel(
    const float* ws, const void* Qm, const void* Rm, const void* Wom,
    const void* bom, void* out) {
    extern __shared__ float smem[];
    if (((const int*)ws)[0] != 0) return;   // bf16 mode handled by e1/e2/e3
    float (*sh_hcat)[LL * HH] = (float (*)[LL * HH])smem;
    float (*sh_r)[HH] = (float (*)[HH])(smem + TT * LL * HH);
    const u16* hhist = (const u16*)(ws + HIST_OFF);
    int tid = threadIdx.x;
    int b = blockIdx.x >> 5;
    int t0 = (blockIdx.x & 31) * TT;

    for (int idx = tid; idx < TT * LL * HH; idx += 256) {
        int tt = idx / (LL * HH);
        int f = idx % (LL * HH);
        int kk = f / HH, j = f % HH;
        sh_hcat[tt][f] = bf2f(hhist[((size_t)((t0 + tt) * 4 + kk) * HH + j) * BB + b]);
    }
    __syncthreads();

    int h0 = tid * 2;
    float acc0[TT] = {0, 0, 0, 0}, acc1[TT] = {0, 0, 0, 0};
    for (int kk = 0; kk < LL; ++kk) {
        float r0[TT] = {0, 0, 0, 0}, r1[TT] = {0, 0, 0, 0};
        const float2* qp = (const float2*)((const float*)Qm + (size_t)kk * (LL * HH) * HH) + tid;
#pragma unroll 4
        for (int f = 0; f < LL * HH; ++f) {
            float2 qv = qp[(size_t)f * 256];
#pragma unroll
            for (int tt = 0; tt < TT; ++tt) {
                float hc = sh_hcat[tt][f];
                r0[tt] += qv.x * hc;
                r1[tt] += qv.y * hc;
            }
        }
        __syncthreads();
#pragma unroll
        for (int tt = 0; tt < TT; ++tt) {
            sh_r[tt][h0]     = 1.f / (1.f + expf(-r0[tt]));
            sh_r[tt][h0 + 1] = 1.f / (1.f + expf(-r1[tt]));
        }
        __syncthreads();
        float m0[TT] = {0, 0, 0, 0}, m1v[TT] = {0, 0, 0, 0};
        const float2* rp = (const float2*)((const float*)Rm + (size_t)kk * HH * HH) + tid;
#pragma unroll 4
        for (int hh2 = 0; hh2 < HH; ++hh2) {
            float2 rv = rp[(size_t)hh2 * 256];
#pragma unroll
            for (int tt = 0; tt < TT; ++tt) {
                float rr = sh_r[tt][hh2];
                m0[tt] += rv.x * rr;
                m1v[tt] += rv.y * rr;
            }
        }
#pragma unroll
        for (int tt = 0; tt < TT; ++tt) {
            acc0[tt] += m0[tt] * sh_hcat[tt][kk * HH + h0];
            acc1[tt] += m1v[tt] * sh_hcat[tt][kk * HH + h0 + 1];
        }
    }
    __syncthreads();
#pragma unroll
    for (int tt = 0; tt < TT; ++tt) {
        sh_r[tt][h0]     = fmaxf(acc0[tt], 0.f);
        sh_r[tt][h0 + 1] = fmaxf(acc1[tt], 0.f);
    }
    __syncthreads();
    {
        int tt = tid >> 6, f = tid & 63;
        float acc = 0.f;
        const float4* wp = (const float4*)((const float*)Wom + (size_t)f * HH);
        const float4* ev = (const float4*)sh_r[tt];
#pragma unroll 8
        for (int it = 0; it < HH / 4; ++it) {
            float4 qv = wp[it], e = ev[it];
            acc += qv.x * e.x + qv.y * e.y + qv.z * e.z + qv.w * e.w;
        }
        acc += ((const float*)bom)[f];
        ((float*)out)[((size_t)b * TS + (t0 + tt)) * FF + f] = acc;
    }
}

// ---- MFMA excite helpers ---------------------------------------------------
__device__ __forceinline__ bfrag8 ld_bfrag(const u16* p) {
    bfrag8 r;
    *(uint2*)&r = *(const uint2*)p;
    *((uint2*)&r + 1) = *(const uint2*)(p + 4);
    return r;
}
__device__ __forceinline__ hfrag8 ld_hfrag(const u16* p) {
    hfrag8 r;
    *(uint2*)&r = *(const uint2*)p;
    *((uint2*)&r + 1) = *(const uint2*)(p + 4);
    return r;
}
__device__ __forceinline__ void st8(u16* p, const u16* v) {
    *(uint2*)p = *(const uint2*)v;
    *(uint2*)(p + 4) = *(const uint2*)(v + 4);
}

// E1: r[k*512+h][col] = sigmoid( sum_f Q[k][f][h] * hcat[f][col] ), fp16 out.
// Grid 256: mb(16) x nb(16). Tile 128x128, K=2048 in 32-chunks.
__global__ __launch_bounds__(256) void e1_kernel(float* ws, const void* Qm, int ts) {
    __shared__ __align__(16) u16 wA[128 * 36];
    __shared__ __align__(16) u16 wB[128 * 36];
    if (((const int*)ws)[0] == 0) return;
    const u16* Q = (const u16*)Qm;
    const u16* hist = (const u16*)(ws + HIST_OFF);
    u16* rbuf = (u16*)(ws + R_OFF);
    int tid = threadIdx.x;
    int mb = blockIdx.x >> 4, nb = blockIdx.x & 15;
    int kq = mb >> 2, h0 = (mb & 3) * 128;
    int colbase = nb * 128;
    int wv = tid >> 6, lane = tid & 63;
    int m = lane & 15, qd = lane >> 4;
    int sr = tid >> 1, fh = (tid & 1) * 16;
    int colg_s = colbase + sr;
    int t_s = ts + (colg_s >> 6), b_s = colg_s & 63;

    facc4 acc[2][8];
#pragma unroll
    for (int i = 0; i < 2; ++i)
#pragma unroll
        for (int j = 0; j < 8; ++j) acc[i][j] = (facc4){0.f, 0.f, 0.f, 0.f};

    for (int fc = 0; fc < 64; ++fc) {
        int f0 = fc * 32;
        __syncthreads();
        {
            u16 tmp[16] __attribute__((aligned(8)));
            const u16* qp = Q + ((size_t)kq * 2048 + f0 + fh) * 512 + h0 + sr;
#pragma unroll
            for (int jj = 0; jj < 16; ++jj) tmp[jj] = qp[(size_t)jj * 512];
            st8(&wA[sr * 36 + fh], tmp);
            st8(&wA[sr * 36 + fh + 8], tmp + 8);
        }
        {
            int kk = f0 >> 9, j0 = f0 & 511;
            u16 tmp[16] __attribute__((aligned(8)));
            const u16* hp = hist + ((size_t)(t_s * 4 + kk) * 512 + j0 + fh) * 64 + b_s;
#pragma unroll
            for (int jj = 0; jj < 16; ++jj) tmp[jj] = hp[(size_t)jj * 64];
            st8(&wB[sr * 36 + fh], tmp);
            st8(&wB[sr * 36 + fh + 8], tmp + 8);
        }
        __syncthreads();
        bfrag8 a0 = ld_bfrag(&wA[(wv * 32 + m) * 36 + qd * 8]);
        bfrag8 a1 = ld_bfrag(&wA[(wv * 32 + 16 + m) * 36 + qd * 8]);
#pragma unroll
        for (int nt = 0; nt < 8; ++nt) {
            bfrag8 bfr = ld_bfrag(&wB[(nt * 16 + m) * 36 + qd * 8]);
            acc[0][nt] = __builtin_amdgcn_mfma_f32_16x16x32_bf16(a0, bfr, acc[0][nt], 0, 0, 0);
            acc[1][nt] = __builtin_amdgcn_mfma_f32_16x16x32_bf16(a1, bfr, acc[1][nt], 0, 0, 0);
        }
    }
#pragma unroll
    for (int mt = 0; mt < 2; ++mt)
#pragma unroll
        for (int nt = 0; nt < 8; ++nt)
#pragma unroll
            for (int reg = 0; reg < 4; ++reg) {
                int row = mb * 128 + wv * 32 + mt * 16 + qd * 4 + reg;
                int col = colbase + nt * 16 + m;
                _Float16 hv = (_Float16)sigm(acc[mt][nt][reg]);
                rbuf[(size_t)row * 2048 + col] = *(u16*)&hv;
            }
}

// E2: excited[g][col] = relu( sum_k (sum_h r[k][h][col]*R[k][h][g]) * hbg )
// Grid 64: gb(4) x cb(16). Tile 128x128, K=512 per k, f16 MFMA.
__global__ __launch_bounds__(256) void e2_kernel(float* ws, const void* Rm, int ts) {
    __shared__ __align__(16) u16 wA[128 * 36];
    __shared__ __align__(16) u16 wB[128 * 36];
    if (((const int*)ws)[0] == 0) return;
    const u16* R = (const u16*)Rm;
    const u16* hist = (const u16*)(ws + HIST_OFF);
    const u16* rbuf = (const u16*)(ws + R_OFF);
    u16* ebuf = (u16*)(ws + EXC_OFF);
    int tid = threadIdx.x;
    int gb = blockIdx.x >> 4, cb = blockIdx.x & 15;
    int colbase = cb * 128;
    int wv = tid >> 6, lane = tid & 63;
    int m = lane & 15, qd = lane >> 4;
    int sr = tid >> 1, fh = (tid & 1) * 16;

    facc4 exc[2][8];
#pragma unroll
    for (int i = 0; i < 2; ++i)
#pragma unroll
        for (int j = 0; j < 8; ++j) exc[i][j] = (facc4){0.f, 0.f, 0.f, 0.f};

    for (int k = 0; k < 4; ++k) {
        facc4 mul[2][8];
#pragma unroll
        for (int i = 0; i < 2; ++i)
#pragma unroll
            for (int j = 0; j < 8; ++j) mul[i][j] = (facc4){0.f, 0.f, 0.f, 0.f};
        for (int hc = 0; hc < 16; ++hc) {
            int hh0 = hc * 32;
            __syncthreads();
            {   // A = R[k][h][g] transposed to [g][h], bf16 -> f16
                u16 tmp[16] __attribute__((aligned(8)));
                const u16* rp = R + ((size_t)k * 512 + hh0 + fh) * 512 + gb * 128 + sr;
#pragma unroll
                for (int jj = 0; jj < 16; ++jj) {
                    _Float16 hv = (_Float16)bf2f(rp[(size_t)jj * 512]);
                    tmp[jj] = *(u16*)&hv;
                }
                st8(&wA[sr * 36 + fh], tmp);
                st8(&wA[sr * 36 + fh + 8], tmp + 8);
            }
            {   // B = r[k*512+h][col] (f16 passthrough)
                u16 tmp[16] __attribute__((aligned(8)));
                const u16* bp = rbuf + ((size_t)(k * 512 + hh0 + fh)) * 2048 + colbase + sr;
#pragma unroll
                for (int jj = 0; jj < 16; ++jj) tmp[jj] = bp[(size_t)jj * 2048];
                st8(&wB[sr * 36 + fh], tmp);
                st8(&wB[sr * 36 + fh + 8], tmp + 8);
            }
            __syncthreads();
            hfrag8 a0 = ld_hfrag(&wA[(wv * 32 + m) * 36 + qd * 8]);
            hfrag8 a1 = ld_hfrag(&wA[(wv * 32 + 16 + m) * 36 + qd * 8]);
#pragma unroll
            for (int nt = 0; nt < 8; ++nt) {
                hfrag8 bfr = ld_hfrag(&wB[(nt * 16 + m) * 36 + qd * 8]);
                mul[0][nt] = __builtin_amdgcn_mfma_f32_16x16x32_f16(a0, bfr, mul[0][nt], 0, 0, 0);
                mul[1][nt] = __builtin_amdgcn_mfma_f32_16x16x32_f16(a1, bfr, mul[1][nt], 0, 0, 0);
            }
        }
        // fold hbg
#pragma unroll
        for (int mt = 0; mt < 2; ++mt)
#pragma unroll
            for (int nt = 0; nt < 8; ++nt)
#pragma unroll
                for (int reg = 0; reg < 4; ++reg) {
                    int g = gb * 128 + wv * 32 + mt * 16 + qd * 4 + reg;
                    int colg = colbase + nt * 16 + m;
                    int t = ts + (colg >> 6), b = colg & 63;
                    float hb = bf2f(hist[((size_t)(t * 4 + k) * 512 + g) * 64 + b]);
                    exc[mt][nt][reg] += mul[mt][nt][reg] * hb;
                }
    }
#pragma unroll
    for (int mt = 0; mt < 2; ++mt)
#pragma unroll
        for (int nt = 0; nt < 8; ++nt)
#pragma unroll
            for (int reg = 0; reg < 4; ++reg) {
                int g = gb * 128 + wv * 32 + mt * 16 + qd * 4 + reg;
                int colg = colbase + nt * 16 + m;
                ebuf[(size_t)g * 2048 + colg] = f2bf_rne(fmaxf(exc[mt][nt][reg], 0.f));
            }
}

// E3: out[b][t][f] = sum_g excited[g][col] * Wo[f][g] + bo[f]. Grid 16 (cols).
__global__ __launch_bounds__(256) void e3_kernel(float* ws, const void* Wom,
                                                 const void* bom, void* outv, int ts) {
    __shared__ __align__(16) u16 wA[64 * 36];
    __shared__ __align__(16) u16 wB[128 * 36];
    if (((const int*)ws)[0] == 0) return;
    const u16* Wo = (const u16*)Wom;
    const u16* bo = (const u16*)bom;
    const u16* ebuf = (const u16*)(ws + EXC_OFF);
    u16* out = (u16*)outv;
    int tid = threadIdx.x;
    int colbase = blockIdx.x * 128;
    int wv = tid >> 6, lane = tid & 63;
    int m = lane & 15, qd = lane >> 4;
    int sr = tid >> 1, fh = (tid & 1) * 16;

    facc4 acc[8];
#pragma unroll
    for (int j = 0; j < 8; ++j) acc[j] = (facc4){0.f, 0.f, 0.f, 0.f};

    for (int gc = 0; gc < 16; ++gc) {
        int g0 = gc * 32;
        __syncthreads();
        {   // A = Wo[f][g] row-major (contraction-minor: direct)
            int r = tid >> 2, q8 = (tid & 3) * 8;
            u16 tmp[8] __attribute__((aligned(8)));
            *(uint4*)tmp = *(const uint4*)(Wo + (size_t)r * 512 + g0 + q8);
            st8(&wA[r * 36 + q8], tmp);
        }
        {   // B = excited[g][col] transposed staging
            u16 tmp[16] __attribute__((aligned(8)));
            const u16* bp = ebuf + ((size_t)(g0 + fh)) * 2048 + colbase + sr;
#pragma unroll
            for (int jj = 0; jj < 16; ++jj) tmp[jj] = bp[(size_t)jj * 2048];
            st8(&wB[sr * 36 + fh], tmp);
            st8(&wB[sr * 36 + fh + 8], tmp + 8);
        }
        __syncthreads();
        bfrag8 a = ld_bfrag(&wA[(wv * 16 + m) * 36 + qd * 8]);
#pragma unroll
        for (int nt = 0; nt < 8; ++nt) {
            bfrag8 bfr = ld_bfrag(&wB[(nt * 16 + m) * 36 + qd * 8]);
            acc[nt] = __builtin_amdgcn_mfma_f32_16x16x32_bf16(a, bfr, acc[nt], 0, 0, 0);
        }
    }
    int f0 = wv * 16 + qd * 4;
    float b0v = bf2f(bo[f0]), b1v = bf2f(bo[f0 + 1]);
    float b2v = bf2f(bo[f0 + 2]), b3v = bf2f(bo[f0 + 3]);
#pragma unroll
    for (int nt = 0; nt < 8; ++nt) {
        int colg = colbase + nt * 16 + m;
        int t = ts + (colg >> 6), b = colg & 63;
        u16 o4[4] __attribute__((aligned(8)));
        o4[0] = f2bf_rne(acc[nt][0] + b0v);
        o4[1] = f2bf_rne(acc[nt][1] + b1v);
        o4[2] = f2bf_rne(acc[nt][2] + b2v);
        o4[3] = f2bf_rne(acc[nt][3] + b3v);
        *(uint2*)&out[((size_t)b * TS + t) * FF + f0] = *(uint2*)o4;
    }
}

extern "C" void kernel_launch(void* const* d_in, const int* in_sizes, int n_in,
                              void* d_out, int out_size, void* d_ws, size_t ws_size,
                              hipStream_t stream) {
    const void* xin = d_in[0];
    const void* Wm  = d_in[1];
    const void* Zm  = d_in[2];
    const void* Um  = d_in[3];
    const void* Vm  = d_in[4];
    const void* Jm  = d_in[5];
    const void* bb  = d_in[6];
    const void* bnd = d_in[7];
    const void* Qm  = d_in[8];
    const void* Rm  = d_in[9];
    const void* Wo  = d_in[10];
    const void* bo  = d_in[11];
    float* ws = (float*)d_ws;

    initA_kernel<<<dim3(512), dim3(256), 0, stream>>>((const u16*)bnd, ws);
    initB_kernel<<<dim3(512), dim3(64), 0, stream>>>(xin, ws);
    for (int tau = 0; tau < 2 * TS + LL - 2; ++tau) {
        gemm_phase_kernel<<<dim3(768), dim3(256), 0, stream>>>(Wm, Zm, Um, Vm, bnd, ws, tau);
        gates_phase_kernel<<<dim3(256), dim3(256), 0, stream>>>(xin, Um, Jm, bb, bnd, ws, tau);
    }
    // f32-mode fallback excite (no-op in bf16 mode)
    size_t exc_smem = (TT * LL * HH + TT * HH) * sizeof(float);
    excite_f32_kernel<<<dim3(2048), dim3(256), exc_smem, stream>>>(
        ws, Qm, Rm, Wo, bo, d_out);
    // bf16-mode MFMA excite: 4 slices of 32 timesteps
    for (int s = 0; s < 4; ++s) {
        int ts = s * 32;
        e1_kernel<<<dim3(256), dim3(256), 0, stream>>>(ws, Qm, ts);
        e2_kernel<<<dim3(64), dim3(256), 0, stream>>>(ws, Rm, ts);
        e3_kernel<<<dim3(16), dim3(256), 0, stream>>>(ws, Wo, bo, d_out, ts);
    }
}

// Round 9
// 6669.608 us; speedup vs baseline: 5.2709x; 1.0063x over previous
//
#include <hip/hip_runtime.h>
#include <hip/hip_bf16.h>

// ---------------------------------------------------------------------------
// StandardMRALSTM — round 9: R6 scan (verbatim) + excite with FIXED staging.
//  * R8 lesson: e1/e2/e3 MFMAs were fed by scalar strided global gathers
//    (1-4KB stride u16 loads) -> same latency-bound pathology as R2/R7.
//  * Fix: coalesced uint4 global reads + LDS-mediated transpose; r stored
//    [col][kq*512+h], excited [col][g] so E2/E3 staging is direct copies.
//    hbg fold via per-k LDS tile (pure coalesced copy). Stride-40 LDS rows.
//  * Numerics identical to R8 (passed, absmax 6.1e-5).
// ---------------------------------------------------------------------------

#define LL 4
#define HH 512
#define TS 128
#define GG 16
#define BB 64
#define FF 64
#define TT 4
#define FIVE_H 2560
#define LBH (LL * BB * HH)

typedef unsigned short u16;
typedef unsigned int u32;
typedef unsigned long long u64;

typedef short bfrag8 __attribute__((ext_vector_type(8)));     // 8 bf16
typedef _Float16 hfrag8 __attribute__((ext_vector_type(8)));  // 8 f16
typedef float facc4 __attribute__((ext_vector_type(4)));      // 4 fp32

#define SG_OFF    64
#define ZALL_OFF  1024
#define ZMASK_OFF 2048
#define C_OFF     4096
#define PING_OFF  (C_OFF + LBH)                       // 135168
#define PART_OFF  (PING_OFF + 2 * LBH)                // 397312
#define PART_SEG  (12 * 4 * HH * BB)                  // 1572864 floats per seg
#define HIST_OFF  (PART_OFF + 2 * PART_SEG)           // 3543040 (u16 region)

// excite scratch (dead scan region after the scan finishes)
#define R_OFF     1024                                 // r fp16 [2048 col][2048 row] u16 (8MB)
#define EXC_OFF   (R_OFF + 2048 * 2048 / 2)            // excited bf16 [2048 col][512 g] u16 (2MB)

__device__ __forceinline__ float bf2f(u16 u) { return __uint_as_float(((u32)u) << 16); }
__device__ __forceinline__ float2 bf2x2(u32 u) {
    float2 r;
    r.x = __uint_as_float(u << 16);
    r.y = __uint_as_float(u & 0xFFFF0000u);
    return r;
}
__device__ __forceinline__ u16 f2bf_rne(float f) {
    u32 x = __float_as_uint(f);
    return (u16)((x + 0x7FFFu + ((x >> 16) & 1u)) >> 16);
}
__device__ __forceinline__ float sigm(float x) { return 1.f / (1.f + expf(-x)); }

template <bool BF>
__device__ __forceinline__ float ldv(const void* p, size_t i) {
    return BF ? bf2f(((const u16*)p)[i]) : ((const float*)p)[i];
}

template <bool BF>
__device__ __forceinline__ float dot16(const void* row, const float* xs) {
    float s = 0.f;
    if (BF) {
        const uint4* p = (const uint4*)row;
        uint4 a = p[0], b4 = p[1];
        float2 v;
        v = bf2x2(a.x);  s += v.x * xs[0]  + v.y * xs[1];
        v = bf2x2(a.y);  s += v.x * xs[2]  + v.y * xs[3];
        v = bf2x2(a.z);  s += v.x * xs[4]  + v.y * xs[5];
        v = bf2x2(a.w);  s += v.x * xs[6]  + v.y * xs[7];
        v = bf2x2(b4.x); s += v.x * xs[8]  + v.y * xs[9];
        v = bf2x2(b4.y); s += v.x * xs[10] + v.y * xs[11];
        v = bf2x2(b4.z); s += v.x * xs[12] + v.y * xs[13];
        v = bf2x2(b4.w); s += v.x * xs[14] + v.y * xs[15];
    } else {
        const float4* p = (const float4*)row;
#pragma unroll
        for (int i = 0; i < 4; ++i) {
            float4 v = p[i];
            s += v.x * xs[4 * i] + v.y * xs[4 * i + 1] + v.z * xs[4 * i + 2] + v.w * xs[4 * i + 3];
        }
    }
    return s;
}

// ---- init A ----------------------------------------------------------------
__global__ void initA_kernel(const u16* __restrict__ bnd_raw, float* __restrict__ ws) {
    size_t i = (size_t)blockIdx.x * 256 + threadIdx.x;
    if (i < LBH) ws[C_OFF + i] = 0.f;
    if (i < 512) ws[SG_OFF + i] = 0.f;
    if (i == 0) {
        int bf = 1;
        for (int j = 0; j < 32; ++j) {
            float v = bf2f(bnd_raw[2 * j]);
            if (!(v >= 0.f && v <= 1.f)) bf = 0;
        }
        ((int*)ws)[0] = bf;
    }
}

// ---- init B ----------------------------------------------------------------
template <bool BF>
__device__ void initB_body(const void* xin, float* ws) {
    int tk = blockIdx.x;
    int t = tk >> 2, k = tk & 3;
    int b = threadIdx.x;
    bool z = false;
    size_t base = (size_t)b * TS * FF + (size_t)t * FF + k * GG;
#pragma unroll
    for (int g = 0; g < GG; ++g) {
        float v = ldv<BF>(xin, base + g);
        z |= !(v != v);
    }
    u64 m = __ballot(z);
    if (b == 0) {
        ((u64*)(ws + ZMASK_OFF))[tk] = m;
        ((int*)(ws + ZALL_OFF))[tk] = (m == ~0ull) ? 1 : 0;
    }
}
__global__ __launch_bounds__(64) void initB_kernel(const void* xin, float* ws) {
    int mode = ((const int*)ws)[0];
    if (mode) initB_body<true>(xin, ws);
    else      initB_body<false>(xin, ws);
}

// ---- per-phase metadata ----------------------------------------------------
template <bool BF>
__device__ __forceinline__ void phase_meta(const void* bnd, const float* ws,
                                           int tau, int s,
                                           int& t, int& k, int& mcase, int& azf, int& nblk) {
    k = (tau & 1) + 2 * s;
    t = (tau - k) >> 1;
    mcase = 4; azf = 0; nblk = 0;
    if (t < 0 || t >= TS) { t = -1; return; }
    const float* sgsum = ws + SG_OFF;
    bool p_hi = (t == 0) ? (ldv<BF>(bnd, (size_t)k * TS) > 0.5f) : (sgsum[(t - 1) * 4 + k] > 16384.f);
    bool l_hi = (k == 0) ? (ldv<BF>(bnd, (size_t)t) > 0.5f) : (sgsum[t * 4 + (k - 1)] > 16384.f);
    mcase = p_hi ? (l_hi ? 3 : 2) : (l_hi ? 1 : 4);
    azf = ((const int*)(ws + ZALL_OFF))[t * 4 + k] ? 0 : 1;
    if (mcase == 4) return;
    int gs = (mcase == 1) ? 0 : 1, ng = 4 - gs;
    int nW = (t > 0) ? ng : 0;
    int nU = ((mcase == 1 || mcase == 3) && k > 0) ? ng : 0;
    int nV = azf ? nU : 0;
    nblk = (nW + nU + nV) * 32;
}

// ---- unit -> (matrix, gate) routing ----------------------------------------
struct SlotInfo {
    const u16* M16; const float* Mf; int RS; int path; int g;
    const float* hv;
};
template <bool BF>
__device__ __forceinline__ SlotInfo slot_info(
    const void* Wm, const void* Zm, const void* Um, const void* Vm,
    const float* ws, int unit, int t, int k, int mcase) {
    int gs = (mcase == 1) ? 0 : 1, ng = 4 - gs;
    int nW = (t > 0) ? ng : 0;
    int nU = ((mcase == 1 || mcase == 3) && k > 0) ? ng : 0;
    int mat, g;
    if (unit < nW)            { mat = (mcase == 1) ? 0 : 1; g = gs + unit; }
    else if (unit < nW + nU)  { mat = 2; g = gs + unit - nW; }
    else                      { mat = 3; g = gs + unit - nW - nU; }
    const void* M = (mat == 0) ? Wm : (mat == 1) ? Zm : (mat == 2) ? Um : Vm;
    int kn = (k + 1 < LL) ? k + 1 : LL - 1;
    const float* ping = ws + PING_OFF;
    const float* prev = ping + (size_t)((t + 1) & 1) * LBH;   // [k][c][b]
    const float* cur  = ping + (size_t)(t & 1) * LBH;
    SlotInfo si;
    si.M16 = (const u16*)M; si.Mf = (const float*)M;
    si.RS = (mat == 2) ? (HH + GG) : HH;
    si.path = (mat <= 1) ? 0 : (mat == 2 ? 1 : 2);
    si.g = g;
    si.hv = (mat == 0) ? prev + (size_t)k * HH * BB
          : (mat == 1) ? prev + (size_t)kn * HH * BB
                       : cur + (size_t)(k - 1) * HH * BB;
    return si;
}

// ---- MFMA gemm slot (BF mode) — R6-proven ----------------------------------
#define WT_STRIDE 152
#define HB_OFF 9728
#define HB_PART 8192
__device__ void gemm_slot_bf(const void* Wm, const void* Zm, const void* Um, const void* Vm,
                             float* ws, u16* gsm,
                             int seg, int idx, int t, int k, int mcase) {
    int tid = threadIdx.x;
    int q = idx & 3, sub = (idx >> 2) & 7, unit = idx >> 5;
    SlotInfo si = slot_info<true>(Wm, Zm, Um, Vm, ws, unit, t, k, mcase);
    int gbase = (si.g < 3) ? si.g * 512 : 2048;
    size_t mbase = (size_t)k * FIVE_H * si.RS + (size_t)(gbase + sub * 64) * si.RS + q * 128;
    u16* wt = gsm;
    u16* hB = gsm + HB_OFF;

    {
        int r = tid >> 2, c0 = (tid & 3) * 32;
        const u16* src = si.M16 + mbase + (size_t)r * si.RS + c0;
#pragma unroll
        for (int i = 0; i < 4; ++i)
            *(uint4*)&wt[r * WT_STRIDE + c0 + 8 * i] = *(const uint4*)(src + 8 * i);
    }
    {
        int wave = tid >> 6, lane = tid & 63;
        int bg = lane >> 4, n = lane & 15;
#pragma unroll
        for (int it = 0; it < 4; ++it) {
            int kbq = it * 4 + wave;
            u32 hiw[4], low[4];
#pragma unroll
            for (int jp = 0; jp < 4; ++jp) {
                float v0 = si.hv[(size_t)(q * 128 + kbq * 8 + 2 * jp) * BB + lane];
                float v1 = si.hv[(size_t)(q * 128 + kbq * 8 + 2 * jp + 1) * BB + lane];
                u16 h0 = f2bf_rne(v0), h1 = f2bf_rne(v1);
                u16 l0 = f2bf_rne(v0 - bf2f(h0)), l1 = f2bf_rne(v1 - bf2f(h1));
                hiw[jp] = (u32)h0 | ((u32)h1 << 16);
                low[jp] = (u32)l0 | ((u32)l1 << 16);
            }
            int base = (kbq * 4 + bg) * 128 + n * 8;
            *(uint4*)&hB[base] = make_uint4(hiw[0], hiw[1], hiw[2], hiw[3]);
            *(uint4*)&hB[HB_PART + base] = make_uint4(low[0], low[1], low[2], low[3]);
        }
    }
    __syncthreads();

    int wave = tid >> 6, lane = tid & 63;
    int m = lane & 15, qd = lane >> 4;
    facc4 acc[4];
#pragma unroll
    for (int i = 0; i < 4; ++i) acc[i] = (facc4){0.f, 0.f, 0.f, 0.f};
#pragma unroll
    for (int kb = 0; kb < 4; ++kb) {
        bfrag8 a = *(const bfrag8*)&wt[(wave * 16 + m) * WT_STRIDE + kb * 32 + qd * 8];
        int kbq = kb * 4 + qd;
#pragma unroll
        for (int bg = 0; bg < 4; ++bg) {
            bfrag8 bh = *(const bfrag8*)&hB[(kbq * 4 + bg) * 128 + m * 8];
            bfrag8 bl = *(const bfrag8*)&hB[HB_PART + (kbq * 4 + bg) * 128 + m * 8];
            acc[bg] = __builtin_amdgcn_mfma_f32_16x16x32_bf16(a, bh, acc[bg], 0, 0, 0);
            acc[bg] = __builtin_amdgcn_mfma_f32_16x16x32_bf16(a, bl, acc[bg], 0, 0, 0);
        }
    }
    float* pout = ws + PART_OFF + (size_t)seg * PART_SEG +
                  ((size_t)(si.path * 4 + q) * 4 + si.g) * (size_t)HH * BB;
#pragma unroll
    for (int bg = 0; bg < 4; ++bg)
#pragma unroll
        for (int reg = 0; reg < 4; ++reg)
            pout[(size_t)(sub * 64 + wave * 16 + qd * 4 + reg) * BB + bg * 16 + m] = acc[bg][reg];
}

// ---- fp32 gemm slot (f32 mode) ---------------------------------------------
__device__ void gemm_slot_f32(const void* Wm, const void* Zm, const void* Um, const void* Vm,
                              float* ws, float* wt, float* ht,
                              int seg, int idx, int t, int k, int mcase) {
    int tid = threadIdx.x;
    int q = idx & 3, sub = (idx >> 2) & 7, unit = idx >> 5;
    SlotInfo si = slot_info<false>(Wm, Zm, Um, Vm, ws, unit, t, k, mcase);
    int gbase = (si.g < 3) ? si.g * 512 : 2048;
    size_t mbase = (size_t)k * FIVE_H * si.RS + (size_t)(gbase + sub * 64) * si.RS + q * 128;

    int rg = tid >> 4, bg = tid & 15;
    float acc[4][4] = {{0.f}};
    for (int half = 0; half < 2; ++half) {
        int sr = tid >> 2, scg = (tid & 3) * 16;
        size_t rowoff = mbase + (size_t)sr * si.RS + half * 64 + scg;
#pragma unroll
        for (int i = 0; i < 4; ++i)
            *(float4*)&wt[sr * 68 + scg + 4 * i] = *(const float4*)(si.Mf + rowoff + 4 * i);
        int hc = tid >> 2, hb = (tid & 3) * 16;
        const float* hrow = si.hv + (size_t)(q * 128 + half * 64 + hc) * BB + hb;
#pragma unroll
        for (int i = 0; i < 4; ++i)
            *(float4*)&ht[hc * 68 + hb + 4 * i] = *(const float4*)(hrow + 4 * i);
        __syncthreads();
#pragma unroll 4
        for (int kk4 = 0; kk4 < 64; kk4 += 4) {
            float w[4][4], h[4][4];
#pragma unroll
            for (int j = 0; j < 4; ++j)
                *(float4*)w[j] = *(const float4*)&wt[(rg * 4 + j) * 68 + kk4];
#pragma unroll
            for (int j = 0; j < 4; ++j)
                *(float4*)h[j] = *(const float4*)&ht[(kk4 + j) * 68 + bg * 4];
#pragma unroll
            for (int rj = 0; rj < 4; ++rj)
#pragma unroll
                for (int bj = 0; bj < 4; ++bj)
#pragma unroll
                    for (int j = 0; j < 4; ++j)
                        acc[rj][bj] += w[rj][j] * h[j][bj];
        }
        __syncthreads();
    }
    float* pout = ws + PART_OFF + (size_t)seg * PART_SEG +
                  ((size_t)(si.path * 4 + q) * 4 + si.g) * (size_t)HH * BB;
#pragma unroll
    for (int rj = 0; rj < 4; ++rj) {
        float4 vv = make_float4(acc[rj][0], acc[rj][1], acc[rj][2], acc[rj][3]);
        *(float4*)&pout[(size_t)(sub * 64 + rg * 4 + rj) * BB + bg * 4] = vv;
    }
}

__global__ __launch_bounds__(256) void gemm_phase_kernel(
    const void* Wm, const void* Zm, const void* Um, const void* Vm,
    const void* bnd, float* ws, int tau) {
    __shared__ __align__(16) u16 gsm[26112];
    int mode = ((const int*)ws)[0];
    if (mode) {
        int t0, k0, m0, a0, n0, t1, k1, m1, a1, n1;
        phase_meta<true>(bnd, ws, tau, 0, t0, k0, m0, a0, n0);
        phase_meta<true>(bnd, ws, tau, 1, t1, k1, m1, a1, n1);
        int bid = blockIdx.x;
        if (bid < n0)           gemm_slot_bf(Wm, Zm, Um, Vm, ws, gsm, 0, bid, t0, k0, m0);
        else if (bid < n0 + n1) gemm_slot_bf(Wm, Zm, Um, Vm, ws, gsm, 1, bid - n0, t1, k1, m1);
    } else {
        float* fs = (float*)gsm;
        int t0, k0, m0, a0, n0, t1, k1, m1, a1, n1;
        phase_meta<false>(bnd, ws, tau, 0, t0, k0, m0, a0, n0);
        phase_meta<false>(bnd, ws, tau, 1, t1, k1, m1, a1, n1);
        int bid = blockIdx.x;
        if (bid < n0)           gemm_slot_f32(Wm, Zm, Um, Vm, ws, fs, fs + 4352, 0, bid, t0, k0, m0);
        else if (bid < n0 + n1) gemm_slot_f32(Wm, Zm, Um, Vm, ws, fs, fs + 4352, 1, bid - n0, t1, k1, m1);
    }
}

// ---- gates slot ------------------------------------------------------------
template <bool BF>
__device__ void gates_slot(const void* xin, const void* Um, const void* Jm,
                           const void* bbias, float* ws, float* smem,
                           int seg, int jblk, int t, int k, int mcase, int azf) {
    float (*xs)[GG + 1] = (float (*)[GG + 1])smem;
    float* red = smem + BB * (GG + 1);
    int tid = threadIdx.x;
    int j = jblk * 4 + (tid >> 6);
    int b = tid & 63;

    {
        int b2 = tid >> 2, i0 = (tid & 3) * 4;
#pragma unroll
        for (int i = 0; i < 4; ++i) {
            float v = ldv<BF>(xin, (size_t)b2 * TS * FF + (size_t)t * FF + k * GG + i0 + i);
            xs[b2][i0 + i] = (v != v) ? 0.f : v;
        }
    }
    __syncthreads();
    u64 zm = ((const u64*)(ws + ZMASK_OFF))[t * 4 + k];
    bool zb = (zm >> b) & 1ull;

    float* cbuf = ws + C_OFF;
    const float* part = ws + PART_OFF + (size_t)seg * PART_SEG;
    float* cur = ws + PING_OFF + (size_t)(t & 1) * LBH;
    const float* prev = ws + PING_OFF + (size_t)((t + 1) & 1) * LBH;
    u16* hist = (u16*)(ws + HIST_OFF);
    size_t sidx = ((size_t)k * HH + j) * BB + b;

    float hn, sgv;
    if (mcase == 4) {
        float c = cbuf[sidx];
        float o = sigm(ldv<BF>(bbias, (size_t)k * FIVE_H + 1536 + j));
        hn = o * tanhf(c);
        float bsg = ldv<BF>(bbias, (size_t)k * FIVE_H + 2048 + j);
        sgv = fminf(fmaxf((bsg + 1.f) * 0.5f, 0.f), 1.f);
    } else {
        bool hasWZ = (t > 0);
        bool hasU = (k > 0) && (mcase != 2);
        const float* xv = &xs[b][0];
        auto psum = [&](int path, int g) -> float {
            float s = 0.f;
#pragma unroll
            for (int qq = 0; qq < 4; ++qq)
                s += part[(((size_t)(path * 4 + qq) * 4 + g) * HH + j) * BB + b];
            return s;
        };
        auto pre = [&](int g) -> float {
            int gb = (g < 3) ? g * 512 : 2048;
            float s = ldv<BF>(bbias, (size_t)k * FIVE_H + gb + j);
            if (hasWZ) s += psum(0, g);
            if (mcase == 2) {
                if (zb) {
                    const void* row = BF ? (const void*)((const u16*)Jm + (size_t)k * FIVE_H * GG + (size_t)(gb + j) * GG)
                                         : (const void*)((const float*)Jm + (size_t)k * FIVE_H * GG + (size_t)(gb + j) * GG);
                    s += dot16<BF>(row, xv);
                }
            } else {
                if (zb) {
                    if (hasU) s += psum(1, g);
                    const void* row = BF ? (const void*)((const u16*)Um + (size_t)k * FIVE_H * (HH + GG) + (size_t)(gb + j) * (HH + GG) + HH)
                                         : (const void*)((const float*)Um + (size_t)k * FIVE_H * (HH + GG) + (size_t)(gb + j) * (HH + GG) + HH);
                    s += dot16<BF>(row, xv);
                } else {
                    if (hasU && azf) s += psum(2, g);
                }
            }
            return s;
        };
        float preg = pre(1), prei = pre(2), presg = pre(3);
        float gg = tanhf(preg), ii = sigm(prei);
        float cnew;
        if (mcase == 1) {
            float f = sigm(pre(0));
            cnew = f * cbuf[sidx] + ii * gg;
        } else {
            cnew = ii * gg;
        }
        cbuf[sidx] = cnew;
        hn = (t > 0) ? prev[sidx] : 0.f;
        sgv = fminf(fmaxf((presg + 1.f) * 0.5f, 0.f), 1.f);
    }
    cur[sidx] = hn;
    hist[((size_t)(t * 4 + k) * HH + j) * BB + b] = f2bf_rne(hn);

    float s = sgv;
#pragma unroll
    for (int off = 32; off > 0; off >>= 1) s += __shfl_down(s, off);
    if ((tid & 63) == 0) red[tid >> 6] = s;
    __syncthreads();
    if (tid == 0)
        atomicAdd(&ws[SG_OFF + t * 4 + k], red[0] + red[1] + red[2] + red[3]);
}

template <bool BF>
__device__ void gates_phase_body(const void* xin, const void* Um, const void* Jm,
                                 const void* bbias, const void* bnd, float* ws,
                                 float* smem, int tau) {
    int seg = blockIdx.x >> 7, jblk = blockIdx.x & 127;
    int t, k, mc, az, nb;
    phase_meta<BF>(bnd, ws, tau, seg, t, k, mc, az, nb);
    if (t >= 0)
        gates_slot<BF>(xin, Um, Jm, bbias, ws, smem, seg, jblk, t, k, mc, az);
}
__global__ __launch_bounds__(256) void gates_phase_kernel(
    const void* xin, const void* Um, const void* Jm, const void* bbias,
    const void* bnd, float* ws, int tau) {
    __shared__ float smem[BB * (GG + 1) + 4];
    int mode = ((const int*)ws)[0];
    if (mode) gates_phase_body<true>(xin, Um, Jm, bbias, bnd, ws, smem, tau);
    else      gates_phase_body<false>(xin, Um, Jm, bbias, bnd, ws, smem, tau);
}

// ---- old scalar excite (f32 mode ONLY) -------------------------------------
__global__ __launch_bounds__(256) void excite_f32_kernel(
    const float* ws, const void* Qm, const void* Rm, const void* Wom,
    const void* bom, void* out) {
    extern __shared__ float smem[];
    if (((const int*)ws)[0] != 0) return;
    float (*sh_hcat)[LL * HH] = (float (*)[LL * HH])smem;
    float (*sh_r)[HH] = (float (*)[HH])(smem + TT * LL * HH);
    const u16* hhist = (const u16*)(ws + HIST_OFF);
    int tid = threadIdx.x;
    int b = blockIdx.x >> 5;
    int t0 = (blockIdx.x & 31) * TT;

    for (int idx = tid; idx < TT * LL * HH; idx += 256) {
        int tt = idx / (LL * HH);
        int f = idx % (LL * HH);
        int kk = f / HH, j = f % HH;
        sh_hcat[tt][f] = bf2f(hhist[((size_t)((t0 + tt) * 4 + kk) * HH + j) * BB + b]);
    }
    __syncthreads();

    int h0 = tid * 2;
    float acc0[TT] = {0, 0, 0, 0}, acc1[TT] = {0, 0, 0, 0};
    for (int kk = 0; kk < LL; ++kk) {
        float r0[TT] = {0, 0, 0, 0}, r1[TT] = {0, 0, 0, 0};
        const float2* qp = (const float2*)((const float*)Qm + (size_t)kk * (LL * HH) * HH) + tid;
#pragma unroll 4
        for (int f = 0; f < LL * HH; ++f) {
            float2 qv = qp[(size_t)f * 256];
#pragma unroll
            for (int tt = 0; tt < TT; ++tt) {
                float hc = sh_hcat[tt][f];
                r0[tt] += qv.x * hc;
                r1[tt] += qv.y * hc;
            }
        }
        __syncthreads();
#pragma unroll
        for (int tt = 0; tt < TT; ++tt) {
            sh_r[tt][h0]     = 1.f / (1.f + expf(-r0[tt]));
            sh_r[tt][h0 + 1] = 1.f / (1.f + expf(-r1[tt]));
        }
        __syncthreads();
        float m0[TT] = {0, 0, 0, 0}, m1v[TT] = {0, 0, 0, 0};
        const float2* rp = (const float2*)((const float*)Rm + (size_t)kk * HH * HH) + tid;
#pragma unroll 4
        for (int hh2 = 0; hh2 < HH; ++hh2) {
            float2 rv = rp[(size_t)hh2 * 256];
#pragma unroll
            for (int tt = 0; tt < TT; ++tt) {
                float rr = sh_r[tt][hh2];
                m0[tt] += rv.x * rr;
                m1v[tt] += rv.y * rr;
            }
        }
#pragma unroll
        for (int tt = 0; tt < TT; ++tt) {
            acc0[tt] += m0[tt] * sh_hcat[tt][kk * HH + h0];
            acc1[tt] += m1v[tt] * sh_hcat[tt][kk * HH + h0 + 1];
        }
    }
    __syncthreads();
#pragma unroll
    for (int tt = 0; tt < TT; ++tt) {
        sh_r[tt][h0]     = fmaxf(acc0[tt], 0.f);
        sh_r[tt][h0 + 1] = fmaxf(acc1[tt], 0.f);
    }
    __syncthreads();
    {
        int tt = tid >> 6, f = tid & 63;
        float acc = 0.f;
        const float4* wp = (const float4*)((const float*)Wom + (size_t)f * HH);
        const float4* ev = (const float4*)sh_r[tt];
#pragma unroll 8
        for (int it = 0; it < HH / 4; ++it) {
            float4 qv = wp[it], e = ev[it];
            acc += qv.x * e.x + qv.y * e.y + qv.z * e.z + qv.w * e.w;
        }
        acc += ((const float*)bom)[f];
        ((float*)out)[((size_t)b * TS + (t0 + tt)) * FF + f] = acc;
    }
}

// ---- MFMA excite helpers ---------------------------------------------------
__device__ __forceinline__ bfrag8 ld_bfrag(const u16* p) {
    bfrag8 r;
    *(uint4*)&r = *(const uint4*)p;   // 16B-aligned by stride-40 layout
    return r;
}
__device__ __forceinline__ hfrag8 ld_hfrag(const u16* p) {
    hfrag8 r;
    *(uint4*)&r = *(const uint4*)p;
    return r;
}

// E1: r[col][kq*512+h] = sigmoid( sum_f Q[kq][f][h] * hcat[f][col] ), fp16.
// grid 256 = mb(16: kq,h-tile) x nb(16: col-tile 128). K=2048 in 32-chunks.
// Staging: coalesced uint4 reads + LDS transpose (stride-40 u16 rows).
__global__ __launch_bounds__(256) void e1_kernel(float* ws, const void* Qm, int ts) {
    __shared__ __align__(16) u16 wA[128 * 40];
    __shared__ __align__(16) u16 wB[128 * 40];
    if (((const int*)ws)[0] == 0) return;
    const u16* Q = (const u16*)Qm;
    const u16* hist = (const u16*)(ws + HIST_OFF);
    u16* rbuf = (u16*)(ws + R_OFF);
    int tid = threadIdx.x;
    int mb = blockIdx.x >> 4, nb = blockIdx.x & 15;
    int kq = mb >> 2, h0 = (mb & 3) * 128;
    int colbase = nb * 128;
    int wv = tid >> 6, lane = tid & 63;
    int m = lane & 15, qd = lane >> 4;
    int arow = tid >> 3, aseg = tid & 7;                 // A: 32 f-rows x 8 h-segs
    int brow = tid >> 2, btt = brow >> 5, bjl = brow & 31, bseg = tid & 3;  // B: 64 rows x 4 b-segs
    int t0g = ts + (colbase >> 6);

    facc4 acc[2][8];
#pragma unroll
    for (int i = 0; i < 2; ++i)
#pragma unroll
        for (int j = 0; j < 8; ++j) acc[i][j] = (facc4){0.f, 0.f, 0.f, 0.f};

    for (int fc = 0; fc < 64; ++fc) {
        int kk = fc >> 4, j0 = (fc & 15) * 32, f0 = fc * 32;
        __syncthreads();
        {   // A: Q[kq][f0+arow][h0 + aseg*16 ..] coalesced -> wA[h][f] transpose
            u16 tmp[16] __attribute__((aligned(16)));
            const u16* src = Q + ((size_t)kq * 2048 + f0 + arow) * 512 + h0 + aseg * 16;
            *(uint4*)tmp = *(const uint4*)src;
            *(uint4*)(tmp + 8) = *(const uint4*)(src + 8);
#pragma unroll
            for (int i = 0; i < 16; ++i) wA[(aseg * 16 + i) * 40 + arow] = tmp[i];
        }
        {   // B: hist[(t,kk)][j0+bjl][bseg*16 ..] coalesced -> wB[col][f=j]
            u16 tmp[16] __attribute__((aligned(16)));
            const u16* src = hist + ((size_t)((t0g + btt) * 4 + kk) * 512 + j0 + bjl) * 64 + bseg * 16;
            *(uint4*)tmp = *(const uint4*)src;
            *(uint4*)(tmp + 8) = *(const uint4*)(src + 8);
#pragma unroll
            for (int i = 0; i < 16; ++i) wB[(btt * 64 + bseg * 16 + i) * 40 + bjl] = tmp[i];
        }
        __syncthreads();
        bfrag8 a0 = ld_bfrag(&wA[(wv * 32 + m) * 40 + qd * 8]);
        bfrag8 a1 = ld_bfrag(&wA[(wv * 32 + 16 + m) * 40 + qd * 8]);
#pragma unroll
        for (int nt = 0; nt < 8; ++nt) {
            bfrag8 bfr = ld_bfrag(&wB[(nt * 16 + m) * 40 + qd * 8]);
            acc[0][nt] = __builtin_amdgcn_mfma_f32_16x16x32_bf16(a0, bfr, acc[0][nt], 0, 0, 0);
            acc[1][nt] = __builtin_amdgcn_mfma_f32_16x16x32_bf16(a1, bfr, acc[1][nt], 0, 0, 0);
        }
    }
#pragma unroll
    for (int mt = 0; mt < 2; ++mt)
#pragma unroll
        for (int nt = 0; nt < 8; ++nt) {
            int hb = h0 + wv * 32 + mt * 16 + qd * 4;
            int col = colbase + nt * 16 + m;
            u16 o4[4] __attribute__((aligned(8)));
#pragma unroll
            for (int reg = 0; reg < 4; ++reg) {
                _Float16 hv = (_Float16)sigm(acc[mt][nt][reg]);
                o4[reg] = *(u16*)&hv;
            }
            *(uint2*)&rbuf[(size_t)col * 2048 + kq * 512 + hb] = *(uint2*)o4;
        }
}

// E2: excited[col][g] = relu( sum_k (sum_h R[k][h][g]*r[k][h][col]) * hbg ).
// grid 64 = gb(4) x cb(16). f16 MFMA; hbg via per-k LDS tile (coalesced copy).
__global__ __launch_bounds__(256) void e2_kernel(float* ws, const void* Rm, int ts) {
    __shared__ __align__(16) u16 wA[128 * 40];
    __shared__ __align__(16) u16 wB[128 * 40];
    __shared__ __align__(16) u16 hbt[128 * 128];
    if (((const int*)ws)[0] == 0) return;
    const u16* R = (const u16*)Rm;
    const u16* hist = (const u16*)(ws + HIST_OFF);
    const u16* rbuf = (const u16*)(ws + R_OFF);
    u16* ebuf = (u16*)(ws + EXC_OFF);
    int tid = threadIdx.x;
    int gb = blockIdx.x >> 4, cb = blockIdx.x & 15;
    int gbase = gb * 128, colbase = cb * 128;
    int wv = tid >> 6, lane = tid & 63;
    int m = lane & 15, qd = lane >> 4;
    int arow = tid >> 3, aseg = tid & 7;    // A: 32 h-rows x 8 g-segs
    int brow = tid >> 1, bhseg = tid & 1;   // B: 128 col-rows x 2 h-segs
    int hgl = tid & 127, htt = tid >> 7;    // hbt: 128 g x 2 t
    int t0g = ts + (colbase >> 6);

    facc4 exc[2][8];
#pragma unroll
    for (int i = 0; i < 2; ++i)
#pragma unroll
        for (int j = 0; j < 8; ++j) exc[i][j] = (facc4){0.f, 0.f, 0.f, 0.f};

    for (int k = 0; k < 4; ++k) {
        __syncthreads();
        {   // hbt[g][col]: pure coalesced copy (hist rows are b-contiguous)
            const u16* src = hist + ((size_t)((t0g + htt) * 4 + k) * 512 + gbase + hgl) * 64;
            u16* dst = &hbt[hgl * 128 + htt * 64];
#pragma unroll
            for (int i = 0; i < 8; ++i) *(uint4*)(dst + 8 * i) = *(const uint4*)(src + 8 * i);
        }
        facc4 mul[2][8];
#pragma unroll
        for (int i = 0; i < 2; ++i)
#pragma unroll
            for (int j = 0; j < 8; ++j) mul[i][j] = (facc4){0.f, 0.f, 0.f, 0.f};
        for (int hc = 0; hc < 16; ++hc) {
            int hh0 = hc * 32;
            __syncthreads();
            {   // A: R[k][hh0+arow][gbase + aseg*16 ..] coalesced -> wA[g][h] (f16)
                u16 tmp[16] __attribute__((aligned(16)));
                const u16* src = R + ((size_t)k * 512 + hh0 + arow) * 512 + gbase + aseg * 16;
                *(uint4*)tmp = *(const uint4*)src;
                *(uint4*)(tmp + 8) = *(const uint4*)(src + 8);
#pragma unroll
                for (int i = 0; i < 16; ++i) {
                    _Float16 hv = (_Float16)bf2f(tmp[i]);
                    wA[(aseg * 16 + i) * 40 + arow] = *(u16*)&hv;
                }
            }
            {   // B: r[col][k*512+h] rows are h-contiguous -> direct copy
                const u16* src = rbuf + (size_t)(colbase + brow) * 2048 + k * 512 + hh0 + bhseg * 16;
                *(uint4*)&wB[brow * 40 + bhseg * 16] = *(const uint4*)src;
                *(uint4*)&wB[brow * 40 + bhseg * 16 + 8] = *(const uint4*)(src + 8);
            }
            __syncthreads();
            hfrag8 a0 = ld_hfrag(&wA[(wv * 32 + m) * 40 + qd * 8]);
            hfrag8 a1 = ld_hfrag(&wA[(wv * 32 + 16 + m) * 40 + qd * 8]);
#pragma unroll
            for (int nt = 0; nt < 8; ++nt) {
                hfrag8 bfr = ld_hfrag(&wB[(nt * 16 + m) * 40 + qd * 8]);
                mul[0][nt] = __builtin_amdgcn_mfma_f32_16x16x32_f16(a0, bfr, mul[0][nt], 0, 0, 0);
                mul[1][nt] = __builtin_amdgcn_mfma_f32_16x16x32_f16(a1, bfr, mul[1][nt], 0, 0, 0);
            }
        }
#pragma unroll
        for (int mt = 0; mt < 2; ++mt)
#pragma unroll
            for (int nt = 0; nt < 8; ++nt)
#pragma unroll
                for (int reg = 0; reg < 4; ++reg) {
                    float hb = bf2f(hbt[(wv * 32 + mt * 16 + qd * 4 + reg) * 128 + nt * 16 + m]);
                    exc[mt][nt][reg] += mul[mt][nt][reg] * hb;
                }
    }
#pragma unroll
    for (int mt = 0; mt < 2; ++mt)
#pragma unroll
        for (int nt = 0; nt < 8; ++nt) {
            int col = colbase + nt * 16 + m;
            int g4 = gbase + wv * 32 + mt * 16 + qd * 4;
            u16 o4[4] __attribute__((aligned(8)));
#pragma unroll
            for (int reg = 0; reg < 4; ++reg)
                o4[reg] = f2bf_rne(fmaxf(exc[mt][nt][reg], 0.f));
            *(uint2*)&ebuf[(size_t)col * 512 + g4] = *(uint2*)o4;
        }
}

// E3: out[b][t][f] = sum_g Wo[f][g] * excited[col][g] + bo[f]. grid 16.
__global__ __launch_bounds__(256) void e3_kernel(float* ws, const void* Wom,
                                                 const void* bom, void* outv, int ts) {
    __shared__ __align__(16) u16 wA[64 * 40];
    __shared__ __align__(16) u16 wB[128 * 40];
    if (((const int*)ws)[0] == 0) return;
    const u16* Wo = (const u16*)Wom;
    const u16* bo = (const u16*)bom;
    const u16* ebuf = (const u16*)(ws + EXC_OFF);
    u16* out = (u16*)outv;
    int tid = threadIdx.x;
    int colbase = blockIdx.x * 128;
    int wv = tid >> 6, lane = tid & 63;
    int m = lane & 15, qd = lane >> 4;
    int arow = tid >> 2, agseg = tid & 3;   // A: 64 f-rows x 4 g-segs of 8
    int brow = tid >> 1, bgseg = tid & 1;   // B: 128 col-rows x 2 g-segs of 16

    facc4 acc[8];
#pragma unroll
    for (int j = 0; j < 8; ++j) acc[j] = (facc4){0.f, 0.f, 0.f, 0.f};

    for (int gc = 0; gc < 16; ++gc) {
        int g0 = gc * 32;
        __syncthreads();
        {   // A: Wo[f][g] g-contiguous -> direct copy
            *(uint4*)&wA[arow * 40 + agseg * 8] =
                *(const uint4*)(Wo + (size_t)arow * 512 + g0 + agseg * 8);
        }
        {   // B: excited[col][g] g-contiguous -> direct copy
            const u16* src = ebuf + (size_t)(colbase + brow) * 512 + g0 + bgseg * 16;
            *(uint4*)&wB[brow * 40 + bgseg * 16] = *(const uint4*)src;
            *(uint4*)&wB[brow * 40 + bgseg * 16 + 8] = *(const uint4*)(src + 8);
        }
        __syncthreads();
        bfrag8 a = ld_bfrag(&wA[(wv * 16 + m) * 40 + qd * 8]);
#pragma unroll
        for (int nt = 0; nt < 8; ++nt) {
            bfrag8 bfr = ld_bfrag(&wB[(nt * 16 + m) * 40 + qd * 8]);
            acc[nt] = __builtin_amdgcn_mfma_f32_16x16x32_bf16(a, bfr, acc[nt], 0, 0, 0);
        }
    }
    int f0 = wv * 16 + qd * 4;
    float b0v = bf2f(bo[f0]), b1v = bf2f(bo[f0 + 1]);
    float b2v = bf2f(bo[f0 + 2]), b3v = bf2f(bo[f0 + 3]);
#pragma unroll
    for (int nt = 0; nt < 8; ++nt) {
        int col = colbase + nt * 16 + m;
        int t = ts + (col >> 6), b = col & 63;
        u16 o4[4] __attribute__((aligned(8)));
        o4[0] = f2bf_rne(acc[nt][0] + b0v);
        o4[1] = f2bf_rne(acc[nt][1] + b1v);
        o4[2] = f2bf_rne(acc[nt][2] + b2v);
        o4[3] = f2bf_rne(acc[nt][3] + b3v);
        *(uint2*)&out[((size_t)b * TS + t) * FF + f0] = *(uint2*)o4;
    }
}

extern "C" void kernel_launch(void* const* d_in, const int* in_sizes, int n_in,
                              void* d_out, int out_size, void* d_ws, size_t ws_size,
                              hipStream_t stream) {
    const void* xin = d_in[0];
    const void* Wm  = d_in[1];
    const void* Zm  = d_in[2];
    const void* Um  = d_in[3];
    const void* Vm  = d_in[4];
    const void* Jm  = d_in[5];
    const void* bb  = d_in[6];
    const void* bnd = d_in[7];
    const void* Qm  = d_in[8];
    const void* Rm  = d_in[9];
    const void* Wo  = d_in[10];
    const void* bo  = d_in[11];
    float* ws = (float*)d_ws;

    initA_kernel<<<dim3(512), dim3(256), 0, stream>>>((const u16*)bnd, ws);
    initB_kernel<<<dim3(512), dim3(64), 0, stream>>>(xin, ws);
    for (int tau = 0; tau < 2 * TS + LL - 2; ++tau) {
        gemm_phase_kernel<<<dim3(768), dim3(256), 0, stream>>>(Wm, Zm, Um, Vm, bnd, ws, tau);
        gates_phase_kernel<<<dim3(256), dim3(256), 0, stream>>>(xin, Um, Jm, bb, bnd, ws, tau);
    }
    // f32-mode fallback excite (no-op in bf16 mode)
    size_t exc_smem = (TT * LL * HH + TT * HH) * sizeof(float);
    excite_f32_kernel<<<dim3(2048), dim3(256), exc_smem, stream>>>(
        ws, Qm, Rm, Wo, bo, d_out);
    // bf16-mode MFMA excite: 4 slices of 32 timesteps
    for (int s = 0; s < 4; ++s) {
        int ts = s * 32;
        e1_kernel<<<dim3(256), dim3(256), 0, stream>>>(ws, Qm, ts);
        e2_kernel<<<dim3(64), dim3(256), 0, stream>>>(ws, Rm, ts);
        e3_kernel<<<dim3(16), dim3(256), 0, stream>>>(ws, Wo, bo, d_out, ts);
    }
}